// Round 3
// baseline (583.292 us; speedup 1.0000x reference)
//
#include <hip/hip_runtime.h>
#include <hip/hip_cooperative_groups.h>
#include <hip/hip_fp16.h>
#include <stdint.h>

namespace cg = cooperative_groups;

#define NQ   300
#define CDIM 256
#define NH   8
#define HD   32
#define HWK  1024
#define HIDD 512

typedef __attribute__((ext_vector_type(8))) _Float16 f16x8;
typedef __attribute__((ext_vector_type(2))) _Float16 h2v;
typedef __attribute__((ext_vector_type(4))) float f32x4;

// ---- ws byte offsets ----
#define QB_OFF   0          // 300*256 f16 [q][c], scale folded
#define KB_OFF   153600     // 8*1024*32 f16 [h][k][d]
#define VT_OFF   677888     // [256 ch][1024 k] f16
#define PO_OFF   1202176    // [8 kr][300 q][256 c] f32 partial O
#define PL_OFF   3659776    // [8 kr][300 q][8 h] f32 partial exp-sums
#define A16_OFF  3736576    // [300][512] f16 a(q,f)
#define NX_OFF   4043776    // [512] f16 -wx
#define NY_OFF   4044800    // [512] f16 -wy
#define W2_OFF   4045824    // [8][512] f16 W2

// shared-memory union layout (max 22144 B):
// stage1: At f32[32][20] @0 (2560) | Wl f32[32][129] @2560 (16512) -> 19072
// stage2: nwx @0 (1024) | pool @1024 (8192) | w2l @9216 (8320)
//         | pb @17536 (4352) | lsum @21888 (256) -> 22144
// stage3: a_lds @0 (1024) | linv @1024 (32)
#define SMEM_BYTES 22144

__device__ __forceinline__ short f16b(float x){
  _Float16 h = (_Float16)x;
  return __builtin_bit_cast(short, h);
}

__device__ __forceinline__ uint32_t pk_f16(float a, float b){
  auto r = __builtin_amdgcn_cvt_pkrtz(a, b);
  return __builtin_bit_cast(uint32_t, r);
}

// ---------------- stage 1a: prep (f16 CPB tables) ----------------
__device__ __forceinline__ void dev_prep(int idx,
    const float* __restrict__ refp, const float* __restrict__ W1,
    const float* __restrict__ b1, const float* __restrict__ W2,
    char* __restrict__ ws)
{
  short* a16  = (short*)(ws + A16_OFF);
  short* nx16 = (short*)(ws + NX_OFF);
  short* ny16 = (short*)(ws + NY_OFF);
  short* w216 = (short*)(ws + W2_OFF);
  if (idx < NQ*HIDD){
    int q = idx >> 9, f = idx & 511;
    float2 w = ((const float2*)W1)[f];
    float a = fmaf(w.x, refp[2*q], fmaf(w.y, refp[2*q+1], b1[f]));
    a16[idx] = f16b(a);
  } else {
    int j = idx - NQ*HIDD;
    if (j < HIDD){
      float2 w = ((const float2*)W1)[j];
      nx16[j] = f16b(-w.x);
      ny16[j] = f16b(-w.y);
    } else if (j < HIDD + NH*HIDD){
      int e = j - HIDD;
      w216[e] = f16b(W2[e]);
    }
  }
}

// ---------------- stage 1b: projection GEMM unit (bxid < 294) ----------------
// tile = bxid>>1, half = bxid&1; tile 0-18: Q, 19-82: K, 83-146: V.
__device__ __forceinline__ void dev_gemm_unit(int bxid,
    const float* __restrict__ rq, const float* __restrict__ qp,
    const float* __restrict__ rs, const float* __restrict__ spe,
    const float* __restrict__ Wq, const float* __restrict__ bq,
    const float* __restrict__ Wk, const float* __restrict__ bk,
    const float* __restrict__ Wv, const float* __restrict__ bv,
    char* __restrict__ ws, char* __restrict__ smem)
{
  float (*At)[20]  = (float (*)[20])smem;
  float (*Wl)[129] = (float (*)[129])(smem + 2560);

  int tile = bxid >> 1, half = bxid & 1;
  const float *in1, *in2, *W, *bias;
  int r0, M, mode;
  if (tile < 19){
    in1 = rq; in2 = qp; W = Wq; bias = bq; r0 = tile*16; M = NQ; mode = 0;
  } else if (tile < 83){
    in1 = rs; in2 = spe; W = Wk; bias = bk; r0 = (tile-19)*16; M = HWK; mode = 1;
  } else {
    in1 = rs; in2 = spe; W = Wv; bias = bv; r0 = (tile-83)*16; M = HWK; mode = 2;
  }
  int tid = threadIdx.x;
  int n_loc = tid & 127;
  int rg = tid >> 7;
  int n = half*128 + n_loc;
  float acc[8];
  float bv_ = bias[n];
  #pragma unroll
  for (int i=0;i<8;i++) acc[i] = bv_;

  for (int c0 = 0; c0 < CDIM; c0 += 32){
    __syncthreads();
    for (int e = tid; e < 512; e += 256){
      int r = e >> 5, c = e & 31;
      int gr = r0 + r; if (gr >= M) gr = M - 1;
      At[c][r] = in1[gr*CDIM + c0 + c] + in2[gr*CDIM + c0 + c];
    }
    for (int e = tid; e < 4096; e += 256){
      int c = e & 31, nn = e >> 5;
      Wl[c][nn] = W[(half*128 + nn)*CDIM + c0 + c];
    }
    __syncthreads();
    #pragma unroll
    for (int c = 0; c < 32; c++){
      float w = Wl[c][n_loc];
      const float4* ap = (const float4*)&At[c][rg*8];
      float4 a0 = ap[0], a1 = ap[1];
      acc[0] = fmaf(a0.x, w, acc[0]);
      acc[1] = fmaf(a0.y, w, acc[1]);
      acc[2] = fmaf(a0.z, w, acc[2]);
      acc[3] = fmaf(a0.w, w, acc[3]);
      acc[4] = fmaf(a1.x, w, acc[4]);
      acc[5] = fmaf(a1.y, w, acc[5]);
      acc[6] = fmaf(a1.z, w, acc[6]);
      acc[7] = fmaf(a1.w, w, acc[7]);
    }
  }

  if (mode == 0){
    short* qb = (short*)(ws + QB_OFF);
    const float s = 0.17677669529663687f;  // 1/sqrt(32)
    #pragma unroll
    for (int i=0;i<8;i++){
      int gr = r0 + rg*8 + i;
      if (gr < M) qb[gr*CDIM + n] = f16b(acc[i]*s);
    }
  } else if (mode == 1){
    short* kb = (short*)(ws + KB_OFF);
    int h = n >> 5, d = n & 31;
    #pragma unroll
    for (int i=0;i<8;i++){
      int gr = r0 + rg*8 + i;
      if (gr < M) kb[((size_t)h*HWK + gr)*HD + d] = f16b(acc[i]);
    }
  } else {
    short* vt = (short*)(ws + VT_OFF);
    uint32_t p[4];
    #pragma unroll
    for (int i=0;i<4;i++) p[i] = pk_f16(acc[2*i], acc[2*i+1]);
    *(uint4*)(vt + n*HWK + r0 + rg*8) = make_uint4(p[0], p[1], p[2], p[3]);
  }
}

// ---------------- stage 2: fused unit (q0 pair, kr 128-k slab) ----------------
__device__ __forceinline__ void dev_fused_unit(int q0, int kr,
    const short* __restrict__ a16, const short* __restrict__ nx16,
    const short* __restrict__ ny16, const short* __restrict__ w216,
    const short* __restrict__ qb, const short* __restrict__ kb,
    const short* __restrict__ vt, float* __restrict__ po,
    float* __restrict__ pl, char* __restrict__ smem)
{
  int tid = threadIdx.x, wave = tid >> 6, lane = tid & 63;
  int n = lane & 15, qd = lane >> 4;

  _Float16* nwx = (_Float16*)smem;                                   // 1KB
  char* pool = smem + 1024;                                          // 8KB
  _Float16 (*w2l)[520] = (_Float16 (*)[520])(smem + 9216);           // 8.3KB
  _Float16 (*pb)[NH][136] = (_Float16 (*)[NH][136])(smem + 17536);   // 4.3KB
  float (*lsum)[16] = (float (*)[16])(smem + 21888);                 // 256B
  _Float16 (*c1s)[4][HIDD] = (_Float16 (*)[4][HIDD])pool;  // [qq][kyrow-local][f]
  float (*part)[4][NH][32] = (float (*)[4][NH][32])pool;   // [qq][wave][h][d]

  // ---- staging from f16 tables ----
  {
    int f0 = tid * 2;
    h2v ny2 = *(const h2v*)(ny16 + f0);
    h2v nx2 = *(const h2v*)(nx16 + f0);
    *(h2v*)&nwx[f0] = nx2;
    #pragma unroll
    for (int qq = 0; qq < 2; qq++){
      h2v a2 = *(const h2v*)(a16 + (q0+qq)*HIDD + f0);
      #pragma unroll
      for (int r = 0; r < 4; r++){
        _Float16 kyh = (_Float16)(((float)(kr*4 + r) + 0.5f) * (1.0f/32.0f));
        h2v ky2 = {kyh, kyh};
        *(h2v*)&c1s[qq][r][f0] = ny2 * ky2 + a2;    // v_pk_fma_f16
      }
    }
  }
  for (int e = tid; e < 512; e += 256){
    int r = e >> 6, c = e & 63;
    *(f16x8*)&w2l[r][c*8] = *(const f16x8*)(w216 + r*HIDD + c*8);
  }
  // masked q fragments: col n = query (n>>3), head (n&7)
  f16x8 qfrag = *(const f16x8*)(qb + (q0 + (n >> 3))*CDIM + (n & 7)*HD + qd*8);
  f16x8 qm[NH];
  #pragma unroll
  for (int h = 0; h < NH; h++){
    f16x8 z = {0,0,0,0,0,0,0,0};
    qm[h] = ((n & 7) == h) ? qfrag : z;
  }
  __syncthreads();

  const int kyrow = kr*4 + wave;          // global ky row (0..31)
  const int kbase = kyrow * 32;

  // ---- phase 1: logits for both queries ----
  f32x4 acc1[2] = {{0.f,0.f,0.f,0.f},{0.f,0.f,0.f,0.f}};
  #pragma unroll
  for (int t = 0; t < 2; t++){
    int k0 = kbase + t*16;
    #pragma unroll
    for (int h = 0; h < NH; h++){
      f16x8 af = *(const f16x8*)(kb + ((size_t)h*HWK + k0 + n)*HD + qd*8);
      acc1[t] = __builtin_amdgcn_mfma_f32_16x16x32_f16(af, qm[h], acc1[t], 0, 0, 0);
    }
  }

  // ---- phase 2: 4 chains accb[qq][t] += relu(c1_qq - wx*kx) @ W2^T ----
  _Float16 kxAh = (_Float16)(((float)n + 0.5f) * (1.0f/32.0f));
  _Float16 kxBh = (_Float16)(((float)n + 16.5f) * (1.0f/32.0f));
  f16x8 kxA8, kxB8, z8;
  #pragma unroll
  for (int j = 0; j < 8; j++){ kxA8[j] = kxAh; kxB8[j] = kxBh; z8[j] = (_Float16)0.f; }
  f32x4 accb[2][2];
  accb[0][0] = acc1[0]; accb[0][1] = acc1[1];
  accb[1][0] = acc1[0]; accb[1][1] = acc1[1];
  const _Float16* c1r0 = &c1s[0][wave][0];
  const _Float16* c1r1 = &c1s[1][wave][0];
  #pragma unroll 4
  for (int kc = 0; kc < 16; kc++){
    int f0 = kc*32 + qd*8;
    f16x8 c10 = *(const f16x8*)(c1r0 + f0);
    f16x8 c11 = *(const f16x8*)(c1r1 + f0);
    f16x8 wxv = *(const f16x8*)(&nwx[f0]);
    f16x8 bfr = *(const f16x8*)(&w2l[n & 7][f0]);
    #pragma unroll
    for (int t = 0; t < 2; t++){
      f16x8 kx8 = t ? kxB8 : kxA8;
      f16x8 e0 = __builtin_elementwise_max(wxv * kx8 + c10, z8);
      accb[0][t] = __builtin_amdgcn_mfma_f32_16x16x32_f16(e0, bfr, accb[0][t], 0, 0, 0);
      f16x8 e1 = __builtin_elementwise_max(wxv * kx8 + c11, z8);
      accb[1][t] = __builtin_amdgcn_mfma_f32_16x16x32_f16(e1, bfr, accb[1][t], 0, 0, 0);
    }
  }

  // ---- phase 3: exp, pb f16, l partials ----
  int qsel = n >> 3, hsel = n & 7;
  float lacc = 0.f;
  #pragma unroll
  for (int t = 0; t < 2; t++){
    f32x4 a = qsel ? accb[1][t] : accb[0][t];
    float e0 = __expf(a[0]);
    float e1 = __expf(a[1]);
    float e2 = __expf(a[2]);
    float e3 = __expf(a[3]);
    uint2 p2;
    p2.x = pk_f16(e0, e1);
    p2.y = pk_f16(e2, e3);
    *(uint2*)&pb[qsel][hsel][wave*32 + t*16 + qd*4] = p2;
    float s = e0 + e1 + e2 + e3;
    s += __shfl_xor(s, 16);
    s += __shfl_xor(s, 32);
    lacc += s;
  }
  if (lane < 16) lsum[wave][lane] = lacc;

  // ---- phase 4: PV for both queries ----
  #pragma unroll
  for (int h = 0; h < NH; h++){
    int kl = wave*32 + qd*8;
    f16x8 pa = *(const f16x8*)&pb[n & 1][h][kl];
    f16x8 v0 = *(const f16x8*)(vt + ((size_t)(h*HD +      n))*HWK + kr*128 + kl);
    f16x8 v1 = *(const f16x8*)(vt + ((size_t)(h*HD + 16 + n))*HWK + kr*128 + kl);
    f32x4 o0 = {0.f,0.f,0.f,0.f}, o1 = {0.f,0.f,0.f,0.f};
    o0 = __builtin_amdgcn_mfma_f32_16x16x32_f16(pa, v0, o0, 0, 0, 0);
    o1 = __builtin_amdgcn_mfma_f32_16x16x32_f16(pa, v1, o1, 0, 0, 0);
    if (qd == 0){
      part[0][wave][h][n]      = o0[0];   // D row 0 = q0
      part[1][wave][h][n]      = o0[1];   // D row 1 = q1
      part[0][wave][h][16 + n] = o1[0];
      part[1][wave][h][16 + n] = o1[1];
    }
  }
  __syncthreads();

  // ---- combine waves, write partials for both queries ----
  {
    int h = tid >> 5, d = tid & 31;
    #pragma unroll
    for (int qq = 0; qq < 2; qq++){
      float s = part[qq][0][h][d] + part[qq][1][h][d]
              + part[qq][2][h][d] + part[qq][3][h][d];
      po[((size_t)kr*NQ + q0 + qq)*CDIM + tid] = s;
    }
    if (tid < 16){
      float s = lsum[0][tid] + lsum[1][tid] + lsum[2][tid] + lsum[3][tid];
      pl[((size_t)kr*NQ + q0 + (tid >> 3))*NH + (tid & 7)] = s;
    }
  }
}

// ---------------- stage 3: output projection, one unit per query row ----------------
__device__ __forceinline__ void dev_outproj(int q,
    const float* __restrict__ po, const float* __restrict__ pl,
    const float* __restrict__ Wo, const float* __restrict__ bo,
    float* __restrict__ dout, char* __restrict__ smem)
{
  int tid = threadIdx.x;
  float* a_lds = (float*)smem;
  float* linv  = (float*)(smem + 1024);

  float s = 0.f;
  #pragma unroll
  for (int p = 0; p < 8; p++) s += po[((size_t)p*NQ + q)*CDIM + tid];

  if (tid < 64){
    int p = tid >> 3, h = tid & 7;
    float l = pl[((size_t)p*NQ + q)*NH + h];
    l += __shfl_xor(l, 8);
    l += __shfl_xor(l, 16);
    l += __shfl_xor(l, 32);
    if (p == 0) linv[h] = 1.0f / l;
  }
  __syncthreads();
  a_lds[tid] = s * linv[tid >> 5];
  __syncthreads();

  const float4* wrow = (const float4*)(Wo + (size_t)tid*CDIM);
  const float4* av = (const float4*)a_lds;
  float acc0 = bo[tid], acc1 = 0.f, acc2 = 0.f, acc3 = 0.f;
  #pragma unroll 4
  for (int c = 0; c < 64; c += 4){
    float4 w0 = wrow[c+0], a0 = av[c+0];
    float4 w1 = wrow[c+1], a1 = av[c+1];
    float4 w2 = wrow[c+2], a2 = av[c+2];
    float4 w3 = wrow[c+3], a3 = av[c+3];
    acc0 = fmaf(w0.x,a0.x,fmaf(w0.y,a0.y,fmaf(w0.z,a0.z,fmaf(w0.w,a0.w,acc0))));
    acc1 = fmaf(w1.x,a1.x,fmaf(w1.y,a1.y,fmaf(w1.z,a1.z,fmaf(w1.w,a1.w,acc1))));
    acc2 = fmaf(w2.x,a2.x,fmaf(w2.y,a2.y,fmaf(w2.z,a2.z,fmaf(w2.w,a2.w,acc2))));
    acc3 = fmaf(w3.x,a3.x,fmaf(w3.y,a3.y,fmaf(w3.z,a3.z,fmaf(w3.w,a3.w,acc3))));
  }
  dout[(size_t)q*CDIM + tid] = acc0 + acc1 + acc2 + acc3;
}

// ================= single cooperative kernel =================
// grid = 1024 (4 blocks/CU co-resident under __launch_bounds__(256,4), LDS 22.1KB).
// stage 1: bid<294 GEMM, 294<=bid<912 prep. grid.sync.
// stage 2: fused units 0..1199 strided by 1024 (bid<176 loop twice). grid.sync.
// stage 3: bid<300 outproj.
__global__ __launch_bounds__(256, 4) void mega_kernel(
    const float* __restrict__ rq, const float* __restrict__ qp,
    const float* __restrict__ rs, const float* __restrict__ spe,
    const float* __restrict__ Wq, const float* __restrict__ bq,
    const float* __restrict__ Wk, const float* __restrict__ bk,
    const float* __restrict__ Wv, const float* __restrict__ bv,
    const float* __restrict__ refp, const float* __restrict__ W1,
    const float* __restrict__ b1, const float* __restrict__ W2,
    const float* __restrict__ Wo, const float* __restrict__ bo,
    char* __restrict__ ws, float* __restrict__ dout)
{
  __shared__ __align__(16) char smem[SMEM_BYTES];
  int bid = blockIdx.x, tid = threadIdx.x;

  if (bid < 294){
    dev_gemm_unit(bid, rq, qp, rs, spe, Wq, bq, Wk, bk, Wv, bv, ws, smem);
  } else if (bid < 912){
    dev_prep((bid - 294)*256 + tid, refp, W1, b1, W2, ws);
  }
  __threadfence();
  cg::this_grid().sync();

  const short* a16  = (const short*)(ws + A16_OFF);
  const short* nx16 = (const short*)(ws + NX_OFF);
  const short* ny16 = (const short*)(ws + NY_OFF);
  const short* w216 = (const short*)(ws + W2_OFF);
  const short* qb   = (const short*)(ws + QB_OFF);
  const short* kb   = (const short*)(ws + KB_OFF);
  const short* vt   = (const short*)(ws + VT_OFF);
  float* po = (float*)(ws + PO_OFF);
  float* pl = (float*)(ws + PL_OFF);

  for (int u = bid; u < 1200; u += 1024){
    dev_fused_unit((u >> 3)*2, u & 7, a16, nx16, ny16, w216, qb, kb, vt,
                   po, pl, smem);
    __syncthreads();   // protect smem reuse on looped blocks
  }
  __threadfence();
  cg::this_grid().sync();

  if (bid < NQ){
    dev_outproj(bid, po, pl, Wo, bo, dout, smem);
  }
}

// ================= standalone fallback kernels (round-2 verified path) =================
__global__ __launch_bounds__(256) void proj_kernel(
    const float* __restrict__ rq, const float* __restrict__ qp,
    const float* __restrict__ rs, const float* __restrict__ spe,
    const float* __restrict__ Wq, const float* __restrict__ bq,
    const float* __restrict__ Wk, const float* __restrict__ bk,
    const float* __restrict__ Wv, const float* __restrict__ bv,
    const float* __restrict__ refp, const float* __restrict__ W1,
    const float* __restrict__ b1, const float* __restrict__ W2,
    char* __restrict__ ws)
{
  __shared__ __align__(16) char smem[19072];
  int bxid = blockIdx.x;
  if (bxid >= 294){
    dev_prep((bxid - 294)*256 + threadIdx.x, refp, W1, b1, W2, ws);
    return;
  }
  dev_gemm_unit(bxid, rq, qp, rs, spe, Wq, bq, Wk, bk, Wv, bv, ws, smem);
}

__global__ __launch_bounds__(256, 4) void fused_kernel(
    const short* __restrict__ a16, const short* __restrict__ nx16,
    const short* __restrict__ ny16, const short* __restrict__ w216,
    const short* __restrict__ qb, const short* __restrict__ kb,
    const short* __restrict__ vt, float* __restrict__ po,
    float* __restrict__ pl)
{
  __shared__ __align__(16) char smem[SMEM_BYTES];
  int bid = blockIdx.x;
  dev_fused_unit((bid >> 3)*2, bid & 7, a16, nx16, ny16, w216, qb, kb, vt,
                 po, pl, smem);
}

__global__ __launch_bounds__(256) void outproj_kernel(
    const float* __restrict__ po, const float* __restrict__ pl,
    const float* __restrict__ Wo, const float* __restrict__ bo,
    float* __restrict__ dout)
{
  __shared__ __align__(16) char smem[1056];
  dev_outproj(blockIdx.x, po, pl, Wo, bo, dout, smem);
}

extern "C" void kernel_launch(void* const* d_in, const int* in_sizes, int n_in,
                              void* d_out, int out_size, void* d_ws, size_t ws_size,
                              hipStream_t stream)
{
  const float* rq  = (const float*)d_in[0];
  const float* qp  = (const float*)d_in[1];
  const float* rp  = (const float*)d_in[2];
  const float* rs  = (const float*)d_in[3];
  const float* spe = (const float*)d_in[4];
  const float* Wq  = (const float*)d_in[5];
  const float* bq  = (const float*)d_in[6];
  const float* Wk  = (const float*)d_in[7];
  const float* bk  = (const float*)d_in[8];
  const float* Wv  = (const float*)d_in[9];
  const float* bv  = (const float*)d_in[10];
  const float* Wo  = (const float*)d_in[11];
  const float* bo  = (const float*)d_in[12];
  const float* W1  = (const float*)d_in[13];
  const float* b1  = (const float*)d_in[14];
  const float* W2  = (const float*)d_in[15];
  char* ws = (char*)d_ws;
  float* dout = (float*)d_out;

  void* args[] = { (void*)&rq, (void*)&qp, (void*)&rs, (void*)&spe,
                   (void*)&Wq, (void*)&bq, (void*)&Wk, (void*)&bk,
                   (void*)&Wv, (void*)&bv, (void*)&rp, (void*)&W1,
                   (void*)&b1, (void*)&W2, (void*)&Wo, (void*)&bo,
                   (void*)&ws, (void*)&dout };
  hipError_t err = hipLaunchCooperativeKernel((const void*)mega_kernel,
      dim3(1024), dim3(256), args, 0, stream);
  if (err != hipSuccess){
    // fallback: round-2 verified 3-launch path
    proj_kernel<<<912, 256, 0, stream>>>(rq, qp, rs, spe, Wq, bq, Wk, bk,
        Wv, bv, rp, W1, b1, W2, ws);
    fused_kernel<<<1200, 256, 0, stream>>>((const short*)(ws + A16_OFF),
        (const short*)(ws + NX_OFF), (const short*)(ws + NY_OFF),
        (const short*)(ws + W2_OFF), (const short*)(ws + QB_OFF),
        (const short*)(ws + KB_OFF), (const short*)(ws + VT_OFF),
        (float*)(ws + PO_OFF), (float*)(ws + PL_OFF));
    outproj_kernel<<<300, 256, 0, stream>>>((const float*)(ws + PO_OFF),
        (const float*)(ws + PL_OFF), Wo, bo, dout);
  }
}

// Round 4
// 510.365 us; speedup vs baseline: 1.1429x; 1.1429x over previous
//
#include <hip/hip_runtime.h>
#include <hip/hip_fp16.h>
#include <stdint.h>

#define NQ   300
#define CDIM 256
#define NH   8
#define HD   32
#define HWK  1024
#define HIDD 512

typedef __attribute__((ext_vector_type(8))) _Float16 f16x8;
typedef __attribute__((ext_vector_type(2))) _Float16 h2v;
typedef __attribute__((ext_vector_type(4))) float f32x4;

// ---- ws byte offsets ----
#define QB_OFF   0          // 300*256 f16 [q][c], scale folded
#define KB_OFF   153600     // 8*1024*32 f16 [h][k][d]
#define VT_OFF   677888     // [256 ch][1024 k] f16
#define PO_OFF   1202176    // [8 kr][300 q][256 c] f32 partial O
#define PL_OFF   3659776    // [8 kr][300 q][8 h] f32 partial exp-sums
#define A16_OFF  3736576    // [300][512] f16 a(q,f)
#define NX_OFF   4043776    // [512] f16 -wx
#define NY_OFF   4044800    // [512] f16 -wy
#define W2_OFF   4045824    // [8][512] f16 W2
#define BAR_OFF  4056064    // [16] u32 grid-barrier counters (memset to 0 pre-launch)

#define NBLK 512            // grid size; co-resident: VGPR<=256 -> >=2 blk/CU * 256 CU

// shared-memory union layout (max 22144 B)
#define SMEM_BYTES 22144

__device__ __forceinline__ short f16b(float x){
  _Float16 h = (_Float16)x;
  return __builtin_bit_cast(short, h);
}

__device__ __forceinline__ uint32_t pk_f16(float a, float b){
  auto r = __builtin_amdgcn_cvt_pkrtz(a, b);
  return __builtin_bit_cast(uint32_t, r);
}

// one-shot grid barrier: counter pre-zeroed by host memset; each block arrives
// once; thread0 spins with short s_sleep (no deep backoff).
__device__ __forceinline__ void grid_barrier(unsigned* cnt, unsigned target){
  __syncthreads();
  __threadfence();                       // release: make our ws writes visible
  if (threadIdx.x == 0){
    __hip_atomic_fetch_add(cnt, 1u, __ATOMIC_RELEASE, __HIP_MEMORY_SCOPE_AGENT);
    while (__hip_atomic_load(cnt, __ATOMIC_ACQUIRE, __HIP_MEMORY_SCOPE_AGENT) < target){
      __builtin_amdgcn_s_sleep(1);
    }
  }
  __syncthreads();
  __threadfence();                       // acquire: drop stale L2 lines
}

// ---------------- stage 1a: prep (f16 CPB tables) ----------------
__device__ __forceinline__ void dev_prep(int idx,
    const float* __restrict__ refp, const float* __restrict__ W1,
    const float* __restrict__ b1, const float* __restrict__ W2,
    char* __restrict__ ws)
{
  short* a16  = (short*)(ws + A16_OFF);
  short* nx16 = (short*)(ws + NX_OFF);
  short* ny16 = (short*)(ws + NY_OFF);
  short* w216 = (short*)(ws + W2_OFF);
  if (idx < NQ*HIDD){
    int q = idx >> 9, f = idx & 511;
    float2 w = ((const float2*)W1)[f];
    float a = fmaf(w.x, refp[2*q], fmaf(w.y, refp[2*q+1], b1[f]));
    a16[idx] = f16b(a);
  } else {
    int j = idx - NQ*HIDD;
    if (j < HIDD){
      float2 w = ((const float2*)W1)[j];
      nx16[j] = f16b(-w.x);
      ny16[j] = f16b(-w.y);
    } else if (j < HIDD + NH*HIDD){
      int e = j - HIDD;
      w216[e] = f16b(W2[e]);
    }
  }
}

// ---------------- stage 1b: projection GEMM unit (u < 294) ----------------
__device__ __forceinline__ void dev_gemm_unit(int bxid,
    const float* __restrict__ rq, const float* __restrict__ qp,
    const float* __restrict__ rs, const float* __restrict__ spe,
    const float* __restrict__ Wq, const float* __restrict__ bq,
    const float* __restrict__ Wk, const float* __restrict__ bk,
    const float* __restrict__ Wv, const float* __restrict__ bv,
    char* __restrict__ ws, char* __restrict__ smem)
{
  float (*At)[20]  = (float (*)[20])smem;
  float (*Wl)[129] = (float (*)[129])(smem + 2560);

  int tile = bxid >> 1, half = bxid & 1;
  const float *in1, *in2, *W, *bias;
  int r0, M, mode;
  if (tile < 19){
    in1 = rq; in2 = qp; W = Wq; bias = bq; r0 = tile*16; M = NQ; mode = 0;
  } else if (tile < 83){
    in1 = rs; in2 = spe; W = Wk; bias = bk; r0 = (tile-19)*16; M = HWK; mode = 1;
  } else {
    in1 = rs; in2 = spe; W = Wv; bias = bv; r0 = (tile-83)*16; M = HWK; mode = 2;
  }
  int tid = threadIdx.x;
  int n_loc = tid & 127;
  int rg = tid >> 7;
  int n = half*128 + n_loc;
  float acc[8];
  float bv_ = bias[n];
  #pragma unroll
  for (int i=0;i<8;i++) acc[i] = bv_;

  for (int c0 = 0; c0 < CDIM; c0 += 32){
    __syncthreads();
    for (int e = tid; e < 512; e += 256){
      int r = e >> 5, c = e & 31;
      int gr = r0 + r; if (gr >= M) gr = M - 1;
      At[c][r] = in1[gr*CDIM + c0 + c] + in2[gr*CDIM + c0 + c];
    }
    for (int e = tid; e < 4096; e += 256){
      int c = e & 31, nn = e >> 5;
      Wl[c][nn] = W[(half*128 + nn)*CDIM + c0 + c];
    }
    __syncthreads();
    #pragma unroll
    for (int c = 0; c < 32; c++){
      float w = Wl[c][n_loc];
      const float4* ap = (const float4*)&At[c][rg*8];
      float4 a0 = ap[0], a1 = ap[1];
      acc[0] = fmaf(a0.x, w, acc[0]);
      acc[1] = fmaf(a0.y, w, acc[1]);
      acc[2] = fmaf(a0.z, w, acc[2]);
      acc[3] = fmaf(a0.w, w, acc[3]);
      acc[4] = fmaf(a1.x, w, acc[4]);
      acc[5] = fmaf(a1.y, w, acc[5]);
      acc[6] = fmaf(a1.z, w, acc[6]);
      acc[7] = fmaf(a1.w, w, acc[7]);
    }
  }

  if (mode == 0){
    short* qb = (short*)(ws + QB_OFF);
    const float s = 0.17677669529663687f;  // 1/sqrt(32)
    #pragma unroll
    for (int i=0;i<8;i++){
      int gr = r0 + rg*8 + i;
      if (gr < M) qb[gr*CDIM + n] = f16b(acc[i]*s);
    }
  } else if (mode == 1){
    short* kb = (short*)(ws + KB_OFF);
    int h = n >> 5, d = n & 31;
    #pragma unroll
    for (int i=0;i<8;i++){
      int gr = r0 + rg*8 + i;
      if (gr < M) kb[((size_t)h*HWK + gr)*HD + d] = f16b(acc[i]);
    }
  } else {
    short* vt = (short*)(ws + VT_OFF);
    uint32_t p[4];
    #pragma unroll
    for (int i=0;i<4;i++) p[i] = pk_f16(acc[2*i], acc[2*i+1]);
    *(uint4*)(vt + n*HWK + r0 + rg*8) = make_uint4(p[0], p[1], p[2], p[3]);
  }
}

// ---------------- stage 2: fused unit (q0 pair, kr 128-k slab) ----------------
__device__ __forceinline__ void dev_fused_unit(int q0, int kr,
    const short* __restrict__ a16, const short* __restrict__ nx16,
    const short* __restrict__ ny16, const short* __restrict__ w216,
    const short* __restrict__ qb, const short* __restrict__ kb,
    const short* __restrict__ vt, float* __restrict__ po,
    float* __restrict__ pl, char* __restrict__ smem)
{
  int tid = threadIdx.x, wave = tid >> 6, lane = tid & 63;
  int n = lane & 15, qd = lane >> 4;

  _Float16* nwx = (_Float16*)smem;                                   // 1KB
  char* pool = smem + 1024;                                          // 8KB
  _Float16 (*w2l)[520] = (_Float16 (*)[520])(smem + 9216);           // 8.3KB
  _Float16 (*pb)[NH][136] = (_Float16 (*)[NH][136])(smem + 17536);   // 4.3KB
  float (*lsum)[16] = (float (*)[16])(smem + 21888);                 // 256B
  _Float16 (*c1s)[4][HIDD] = (_Float16 (*)[4][HIDD])pool;  // [qq][kyrow-local][f]
  float (*part)[4][NH][32] = (float (*)[4][NH][32])pool;   // [qq][wave][h][d]

  // ---- staging from f16 tables ----
  {
    int f0 = tid * 2;
    h2v ny2 = *(const h2v*)(ny16 + f0);
    h2v nx2 = *(const h2v*)(nx16 + f0);
    *(h2v*)&nwx[f0] = nx2;
    #pragma unroll
    for (int qq = 0; qq < 2; qq++){
      h2v a2 = *(const h2v*)(a16 + (q0+qq)*HIDD + f0);
      #pragma unroll
      for (int r = 0; r < 4; r++){
        _Float16 kyh = (_Float16)(((float)(kr*4 + r) + 0.5f) * (1.0f/32.0f));
        h2v ky2 = {kyh, kyh};
        *(h2v*)&c1s[qq][r][f0] = ny2 * ky2 + a2;    // v_pk_fma_f16
      }
    }
  }
  for (int e = tid; e < 512; e += 256){
    int r = e >> 6, c = e & 63;
    *(f16x8*)&w2l[r][c*8] = *(const f16x8*)(w216 + r*HIDD + c*8);
  }
  // masked q fragments: col n = query (n>>3), head (n&7)
  f16x8 qfrag = *(const f16x8*)(qb + (q0 + (n >> 3))*CDIM + (n & 7)*HD + qd*8);
  f16x8 qm[NH];
  #pragma unroll
  for (int h = 0; h < NH; h++){
    f16x8 z = {0,0,0,0,0,0,0,0};
    qm[h] = ((n & 7) == h) ? qfrag : z;
  }
  __syncthreads();

  const int kyrow = kr*4 + wave;          // global ky row (0..31)
  const int kbase = kyrow * 32;

  // ---- phase 1: logits for both queries ----
  f32x4 acc1[2] = {{0.f,0.f,0.f,0.f},{0.f,0.f,0.f,0.f}};
  #pragma unroll
  for (int t = 0; t < 2; t++){
    int k0 = kbase + t*16;
    #pragma unroll
    for (int h = 0; h < NH; h++){
      f16x8 af = *(const f16x8*)(kb + ((size_t)h*HWK + k0 + n)*HD + qd*8);
      acc1[t] = __builtin_amdgcn_mfma_f32_16x16x32_f16(af, qm[h], acc1[t], 0, 0, 0);
    }
  }

  // ---- phase 2: 4 chains accb[qq][t] += relu(c1_qq - wx*kx) @ W2^T ----
  _Float16 kxAh = (_Float16)(((float)n + 0.5f) * (1.0f/32.0f));
  _Float16 kxBh = (_Float16)(((float)n + 16.5f) * (1.0f/32.0f));
  f16x8 kxA8, kxB8, z8;
  #pragma unroll
  for (int j = 0; j < 8; j++){ kxA8[j] = kxAh; kxB8[j] = kxBh; z8[j] = (_Float16)0.f; }
  f32x4 accb[2][2];
  accb[0][0] = acc1[0]; accb[0][1] = acc1[1];
  accb[1][0] = acc1[0]; accb[1][1] = acc1[1];
  const _Float16* c1r0 = &c1s[0][wave][0];
  const _Float16* c1r1 = &c1s[1][wave][0];
  #pragma unroll 4
  for (int kc = 0; kc < 16; kc++){
    int f0 = kc*32 + qd*8;
    f16x8 c10 = *(const f16x8*)(c1r0 + f0);
    f16x8 c11 = *(const f16x8*)(c1r1 + f0);
    f16x8 wxv = *(const f16x8*)(&nwx[f0]);
    f16x8 bfr = *(const f16x8*)(&w2l[n & 7][f0]);
    #pragma unroll
    for (int t = 0; t < 2; t++){
      f16x8 kx8 = t ? kxB8 : kxA8;
      f16x8 e0 = __builtin_elementwise_max(wxv * kx8 + c10, z8);
      accb[0][t] = __builtin_amdgcn_mfma_f32_16x16x32_f16(e0, bfr, accb[0][t], 0, 0, 0);
      f16x8 e1 = __builtin_elementwise_max(wxv * kx8 + c11, z8);
      accb[1][t] = __builtin_amdgcn_mfma_f32_16x16x32_f16(e1, bfr, accb[1][t], 0, 0, 0);
    }
  }

  // ---- phase 3: exp, pb f16, l partials ----
  int qsel = n >> 3, hsel = n & 7;
  float lacc = 0.f;
  #pragma unroll
  for (int t = 0; t < 2; t++){
    f32x4 a = qsel ? accb[1][t] : accb[0][t];
    float e0 = __expf(a[0]);
    float e1 = __expf(a[1]);
    float e2 = __expf(a[2]);
    float e3 = __expf(a[3]);
    uint2 p2;
    p2.x = pk_f16(e0, e1);
    p2.y = pk_f16(e2, e3);
    *(uint2*)&pb[qsel][hsel][wave*32 + t*16 + qd*4] = p2;
    float s = e0 + e1 + e2 + e3;
    s += __shfl_xor(s, 16);
    s += __shfl_xor(s, 32);
    lacc += s;
  }
  if (lane < 16) lsum[wave][lane] = lacc;

  // ---- phase 4: PV for both queries ----
  #pragma unroll
  for (int h = 0; h < NH; h++){
    int kl = wave*32 + qd*8;
    f16x8 pa = *(const f16x8*)&pb[n & 1][h][kl];
    f16x8 v0 = *(const f16x8*)(vt + ((size_t)(h*HD +      n))*HWK + kr*128 + kl);
    f16x8 v1 = *(const f16x8*)(vt + ((size_t)(h*HD + 16 + n))*HWK + kr*128 + kl);
    f32x4 o0 = {0.f,0.f,0.f,0.f}, o1 = {0.f,0.f,0.f,0.f};
    o0 = __builtin_amdgcn_mfma_f32_16x16x32_f16(pa, v0, o0, 0, 0, 0);
    o1 = __builtin_amdgcn_mfma_f32_16x16x32_f16(pa, v1, o1, 0, 0, 0);
    if (qd == 0){
      part[0][wave][h][n]      = o0[0];   // D row 0 = q0
      part[1][wave][h][n]      = o0[1];   // D row 1 = q1
      part[0][wave][h][16 + n] = o1[0];
      part[1][wave][h][16 + n] = o1[1];
    }
  }
  __syncthreads();

  // ---- combine waves, write partials for both queries ----
  {
    int h = tid >> 5, d = tid & 31;
    #pragma unroll
    for (int qq = 0; qq < 2; qq++){
      float s = part[qq][0][h][d] + part[qq][1][h][d]
              + part[qq][2][h][d] + part[qq][3][h][d];
      po[((size_t)kr*NQ + q0 + qq)*CDIM + tid] = s;
    }
    if (tid < 16){
      float s = lsum[0][tid] + lsum[1][tid] + lsum[2][tid] + lsum[3][tid];
      pl[((size_t)kr*NQ + q0 + (tid >> 3))*NH + (tid & 7)] = s;
    }
  }
}

// ---------------- stage 3: output projection, one unit per query row ----------------
__device__ __forceinline__ void dev_outproj(int q,
    const float* __restrict__ po, const float* __restrict__ pl,
    const float* __restrict__ Wo, const float* __restrict__ bo,
    float* __restrict__ dout, char* __restrict__ smem)
{
  int tid = threadIdx.x;
  float* a_lds = (float*)smem;
  float* linv  = (float*)(smem + 1024);

  float s = 0.f;
  #pragma unroll
  for (int p = 0; p < 8; p++) s += po[((size_t)p*NQ + q)*CDIM + tid];

  if (tid < 64){
    int p = tid >> 3, h = tid & 7;
    float l = pl[((size_t)p*NQ + q)*NH + h];
    l += __shfl_xor(l, 8);
    l += __shfl_xor(l, 16);
    l += __shfl_xor(l, 32);
    if (p == 0) linv[h] = 1.0f / l;
  }
  __syncthreads();
  a_lds[tid] = s * linv[tid >> 5];
  __syncthreads();

  const float4* wrow = (const float4*)(Wo + (size_t)tid*CDIM);
  const float4* av = (const float4*)a_lds;
  float acc0 = bo[tid], acc1 = 0.f, acc2 = 0.f, acc3 = 0.f;
  #pragma unroll 4
  for (int c = 0; c < 64; c += 4){
    float4 w0 = wrow[c+0], a0 = av[c+0];
    float4 w1 = wrow[c+1], a1 = av[c+1];
    float4 w2 = wrow[c+2], a2 = av[c+2];
    float4 w3 = wrow[c+3], a3 = av[c+3];
    acc0 = fmaf(w0.x,a0.x,fmaf(w0.y,a0.y,fmaf(w0.z,a0.z,fmaf(w0.w,a0.w,acc0))));
    acc1 = fmaf(w1.x,a1.x,fmaf(w1.y,a1.y,fmaf(w1.z,a1.z,fmaf(w1.w,a1.w,acc1))));
    acc2 = fmaf(w2.x,a2.x,fmaf(w2.y,a2.y,fmaf(w2.z,a2.z,fmaf(w2.w,a2.w,acc2))));
    acc3 = fmaf(w3.x,a3.x,fmaf(w3.y,a3.y,fmaf(w3.z,a3.z,fmaf(w3.w,a3.w,acc3))));
  }
  dout[(size_t)q*CDIM + tid] = acc0 + acc1 + acc2 + acc3;
}

// ================= single kernel, custom grid barriers =================
// grid = 512 (guaranteed co-resident: __launch_bounds__(256,2) caps VGPR at 256
// -> >=2 blocks/CU; LDS 22.1KB -> 7/CU). Barrier counters pre-zeroed by memset.
__global__ __launch_bounds__(256, 2) void mega_kernel(
    const float* __restrict__ rq, const float* __restrict__ qp,
    const float* __restrict__ rs, const float* __restrict__ spe,
    const float* __restrict__ Wq, const float* __restrict__ bq,
    const float* __restrict__ Wk, const float* __restrict__ bk,
    const float* __restrict__ Wv, const float* __restrict__ bv,
    const float* __restrict__ refp, const float* __restrict__ W1,
    const float* __restrict__ b1, const float* __restrict__ W2,
    const float* __restrict__ Wo, const float* __restrict__ bo,
    char* __restrict__ ws, float* __restrict__ dout)
{
  __shared__ __align__(16) char smem[SMEM_BYTES];
  int bid = blockIdx.x, tid = threadIdx.x;
  unsigned* bar = (unsigned*)(ws + BAR_OFF);

  // ---- stage 1: 294 GEMM units + 618 prep units over 512 blocks ----
  for (int u = bid; u < 912; u += NBLK){
    if (u < 294){
      dev_gemm_unit(u, rq, qp, rs, spe, Wq, bq, Wk, bk, Wv, bv, ws, smem);
    } else {
      dev_prep((u - 294)*256 + tid, refp, W1, b1, W2, ws);
    }
  }
  grid_barrier(&bar[0], NBLK);

  const short* a16  = (const short*)(ws + A16_OFF);
  const short* nx16 = (const short*)(ws + NX_OFF);
  const short* ny16 = (const short*)(ws + NY_OFF);
  const short* w216 = (const short*)(ws + W2_OFF);
  const short* qb   = (const short*)(ws + QB_OFF);
  const short* kb   = (const short*)(ws + KB_OFF);
  const short* vt   = (const short*)(ws + VT_OFF);
  float* po = (float*)(ws + PO_OFF);
  float* pl = (float*)(ws + PL_OFF);

  // ---- stage 2: 1200 fused units over 512 blocks ----
  for (int u = bid; u < 1200; u += NBLK){
    dev_fused_unit((u >> 3)*2, u & 7, a16, nx16, ny16, w216, qb, kb, vt,
                   po, pl, smem);
    __syncthreads();   // protect smem reuse between looped units
  }
  grid_barrier(&bar[8], NBLK);

  // ---- stage 3: 300 outproj units ----
  if (bid < NQ){
    dev_outproj(bid, po, pl, Wo, bo, dout, smem);
  }
}

extern "C" void kernel_launch(void* const* d_in, const int* in_sizes, int n_in,
                              void* d_out, int out_size, void* d_ws, size_t ws_size,
                              hipStream_t stream)
{
  const float* rq  = (const float*)d_in[0];
  const float* qp  = (const float*)d_in[1];
  const float* rp  = (const float*)d_in[2];
  const float* rs  = (const float*)d_in[3];
  const float* spe = (const float*)d_in[4];
  const float* Wq  = (const float*)d_in[5];
  const float* bq  = (const float*)d_in[6];
  const float* Wk  = (const float*)d_in[7];
  const float* bk  = (const float*)d_in[8];
  const float* Wv  = (const float*)d_in[9];
  const float* bv  = (const float*)d_in[10];
  const float* Wo  = (const float*)d_in[11];
  const float* bo  = (const float*)d_in[12];
  const float* W1  = (const float*)d_in[13];
  const float* b1  = (const float*)d_in[14];
  const float* W2  = (const float*)d_in[15];
  char* ws = (char*)d_ws;
  float* dout = (float*)d_out;

  // zero the grid-barrier counters (ws is poisoned by the harness each iter)
  hipMemsetAsync(ws + BAR_OFF, 0, 64, stream);

  mega_kernel<<<NBLK, 256, 0, stream>>>(rq, qp, rs, spe, Wq, bq, Wk, bk,
      Wv, bv, rp, W1, b1, W2, Wo, bo, ws, dout);
}

// Round 5
// 319.182 us; speedup vs baseline: 1.8275x; 1.5990x over previous
//
#include <hip/hip_runtime.h>
#include <hip/hip_fp16.h>
#include <stdint.h>

#define NQ   300
#define CDIM 256
#define NH   8
#define HD   32
#define HWK  1024
#define HIDD 512

typedef __attribute__((ext_vector_type(8))) _Float16 f16x8;
typedef __attribute__((ext_vector_type(2))) _Float16 h2v;
typedef __attribute__((ext_vector_type(4))) float f32x4;

// ---- ws byte offsets ----
#define QB_OFF   0          // 300*256 f16 [q][c], scale folded
#define KB_OFF   153600     // 8*1024*32 f16 [h][k][d]
#define VT_OFF   677888     // [256 ch][1024 k] f16
#define PO_OFF   1202176    // [8 kr][300 q][256 c] f32 partial O
#define PL_OFF   3659776    // [8 kr][300 q][8 h] f32 partial exp-sums
#define A16_OFF  3736576    // [300][512] f16 a(q,f)
#define NX_OFF   4043776    // [512] f16 -wx
#define NY_OFF   4044800    // [512] f16 -wy
#define W2_OFF   4045824    // [8][512] f16 W2
#define QC_OFF   4056064    // [150] u32 per-qpair arrival counters (memset 0)

__device__ __forceinline__ short f16b(float x){
  _Float16 h = (_Float16)x;
  return __builtin_bit_cast(short, h);
}

__device__ __forceinline__ uint32_t pk_f16(float a, float b){
  auto r = __builtin_amdgcn_cvt_pkrtz(a, b);
  return __builtin_bit_cast(uint32_t, r);
}

// ---------------- projection GEMMs + fused prep blocks ----------------
// bxid 0..293: tile = bxid>>1, half = bxid&1
//   tile 0-18  : q -> QB f16 (scaled)
//   tile 19-82 : k -> KB [h][k][d]
//   tile 83-146: v -> VT transposed
// bxid 294..911: prep path (f16 CPB tables), runs concurrently.
__global__ __launch_bounds__(256) void proj_kernel(
    const float* __restrict__ rq, const float* __restrict__ qp,
    const float* __restrict__ rs, const float* __restrict__ spe,
    const float* __restrict__ Wq, const float* __restrict__ bq,
    const float* __restrict__ Wk, const float* __restrict__ bk,
    const float* __restrict__ Wv, const float* __restrict__ bv,
    const float* __restrict__ refp, const float* __restrict__ W1,
    const float* __restrict__ b1, const float* __restrict__ W2,
    char* __restrict__ ws)
{
  int bxid = blockIdx.x;
  __shared__ __align__(16) float At[32][20];
  __shared__ float Wl[32][129];

  if (bxid >= 294){
    // ---- prep path ----
    int idx = (bxid - 294) * 256 + threadIdx.x;
    short* a16  = (short*)(ws + A16_OFF);
    short* nx16 = (short*)(ws + NX_OFF);
    short* ny16 = (short*)(ws + NY_OFF);
    short* w216 = (short*)(ws + W2_OFF);
    if (idx < NQ*HIDD){
      int q = idx >> 9, f = idx & 511;
      float2 w = ((const float2*)W1)[f];
      float a = fmaf(w.x, refp[2*q], fmaf(w.y, refp[2*q+1], b1[f]));
      a16[idx] = f16b(a);
    } else {
      int j = idx - NQ*HIDD;
      if (j < HIDD){
        float2 w = ((const float2*)W1)[j];
        nx16[j] = f16b(-w.x);
        ny16[j] = f16b(-w.y);
      } else if (j < HIDD + NH*HIDD){
        int e = j - HIDD;
        w216[e] = f16b(W2[e]);
      }
    }
    return;
  }

  int tile = bxid >> 1, half = bxid & 1;
  const float *in1, *in2, *W, *bias;
  int r0, M, mode;
  if (tile < 19){
    in1 = rq; in2 = qp; W = Wq; bias = bq; r0 = tile*16; M = NQ; mode = 0;
  } else if (tile < 83){
    in1 = rs; in2 = spe; W = Wk; bias = bk; r0 = (tile-19)*16; M = HWK; mode = 1;
  } else {
    in1 = rs; in2 = spe; W = Wv; bias = bv; r0 = (tile-83)*16; M = HWK; mode = 2;
  }
  int tid = threadIdx.x;
  int n_loc = tid & 127;
  int rg = tid >> 7;
  int n = half*128 + n_loc;
  float acc[8];
  float bv_ = bias[n];
  #pragma unroll
  for (int i=0;i<8;i++) acc[i] = bv_;

  for (int c0 = 0; c0 < CDIM; c0 += 32){
    __syncthreads();
    for (int e = tid; e < 512; e += 256){
      int r = e >> 5, c = e & 31;
      int gr = r0 + r; if (gr >= M) gr = M - 1;
      At[c][r] = in1[gr*CDIM + c0 + c] + in2[gr*CDIM + c0 + c];
    }
    for (int e = tid; e < 4096; e += 256){
      int c = e & 31, nn = e >> 5;
      Wl[c][nn] = W[(half*128 + nn)*CDIM + c0 + c];
    }
    __syncthreads();
    #pragma unroll
    for (int c = 0; c < 32; c++){
      float w = Wl[c][n_loc];
      const float4* ap = (const float4*)&At[c][rg*8];
      float4 a0 = ap[0], a1 = ap[1];
      acc[0] = fmaf(a0.x, w, acc[0]);
      acc[1] = fmaf(a0.y, w, acc[1]);
      acc[2] = fmaf(a0.z, w, acc[2]);
      acc[3] = fmaf(a0.w, w, acc[3]);
      acc[4] = fmaf(a1.x, w, acc[4]);
      acc[5] = fmaf(a1.y, w, acc[5]);
      acc[6] = fmaf(a1.z, w, acc[6]);
      acc[7] = fmaf(a1.w, w, acc[7]);
    }
  }

  if (mode == 0){
    short* qb = (short*)(ws + QB_OFF);
    const float s = 0.17677669529663687f;  // 1/sqrt(32)
    #pragma unroll
    for (int i=0;i<8;i++){
      int gr = r0 + rg*8 + i;
      if (gr < M) qb[gr*CDIM + n] = f16b(acc[i]*s);
    }
  } else if (mode == 1){
    short* kb = (short*)(ws + KB_OFF);
    int h = n >> 5, d = n & 31;
    #pragma unroll
    for (int i=0;i<8;i++){
      int gr = r0 + rg*8 + i;
      if (gr < M) kb[((size_t)h*HWK + gr)*HD + d] = f16b(acc[i]);
    }
  } else {
    short* vt = (short*)(ws + VT_OFF);
    uint32_t p[4];
    #pragma unroll
    for (int i=0;i<4;i++) p[i] = pk_f16(acc[2*i], acc[2*i+1]);
    *(uint4*)(vt + n*HWK + r0 + rg*8) = make_uint4(p[0], p[1], p[2], p[3]);
  }
}

// ---------------- output projection unit (runs inside last fused block) ----------------
__device__ __forceinline__ void dev_outproj(int q,
    const float* __restrict__ po, const float* __restrict__ pl,
    const float* __restrict__ Wo, const float* __restrict__ bo,
    float* __restrict__ dout, char* __restrict__ smem)
{
  int tid = threadIdx.x;
  float* a_lds = (float*)smem;            // 1KB
  float* linv  = (float*)(smem + 1024);   // 32B

  float s = 0.f;
  #pragma unroll
  for (int p = 0; p < 8; p++) s += po[((size_t)p*NQ + q)*CDIM + tid];

  if (tid < 64){
    int p = tid >> 3, h = tid & 7;
    float l = pl[((size_t)p*NQ + q)*NH + h];
    l += __shfl_xor(l, 8);
    l += __shfl_xor(l, 16);
    l += __shfl_xor(l, 32);
    if (p == 0) linv[h] = 1.0f / l;
  }
  __syncthreads();
  a_lds[tid] = s * linv[tid >> 5];
  __syncthreads();

  const float4* wrow = (const float4*)(Wo + (size_t)tid*CDIM);
  const float4* av = (const float4*)a_lds;
  float acc0 = bo[tid], acc1 = 0.f, acc2 = 0.f, acc3 = 0.f;
  #pragma unroll 4
  for (int c = 0; c < 64; c += 4){
    float4 w0 = wrow[c+0], a0 = av[c+0];
    float4 w1 = wrow[c+1], a1 = av[c+1];
    float4 w2 = wrow[c+2], a2 = av[c+2];
    float4 w3 = wrow[c+3], a3 = av[c+3];
    acc0 = fmaf(w0.x,a0.x,fmaf(w0.y,a0.y,fmaf(w0.z,a0.z,fmaf(w0.w,a0.w,acc0))));
    acc1 = fmaf(w1.x,a1.x,fmaf(w1.y,a1.y,fmaf(w1.z,a1.z,fmaf(w1.w,a1.w,acc1))));
    acc2 = fmaf(w2.x,a2.x,fmaf(w2.y,a2.y,fmaf(w2.z,a2.z,fmaf(w2.w,a2.w,acc2))));
    acc3 = fmaf(w3.x,a3.x,fmaf(w3.y,a3.y,fmaf(w3.z,a3.z,fmaf(w3.w,a3.w,acc3))));
  }
  dout[(size_t)q*CDIM + tid] = acc0 + acc1 + acc2 + acc3;
}

// ---------------- fused: logits + CPB + exp + partial PV + last-block outproj ----------------
// grid = 1200: qpair = bid>>3 (q0=2*qpair), kr = bid&7 (128 k). 4 waves.
// After writing po/pl, each block atomically counts arrivals for its qpair;
// the 8th (last) block inlines the output projection for q0, q0+1 — no spinning.
__global__ __launch_bounds__(256, 4) void fused_kernel(
    const short* __restrict__ a16, const short* __restrict__ nx16,
    const short* __restrict__ ny16, const short* __restrict__ w216,
    const short* __restrict__ qb, const short* __restrict__ kb,
    const short* __restrict__ vt, float* __restrict__ po,
    float* __restrict__ pl,
    const float* __restrict__ Wo, const float* __restrict__ bo,
    float* __restrict__ dout, unsigned* __restrict__ qcnt)
{
  int bid = blockIdx.x;
  int q0 = (bid >> 3) * 2, kr = bid & 7;
  int tid = threadIdx.x, wave = tid >> 6, lane = tid & 63;
  int n = lane & 15, qd = lane >> 4;

  __shared__ __align__(16) _Float16 nwx[HIDD];      // 1KB
  __shared__ __align__(16) char pool[8192];         // c1s (ph1-2) / part (ph4) / outproj smem
  __shared__ __align__(16) _Float16 w2l[NH][520];   // 8.3KB
  __shared__ __align__(16) _Float16 pb[2][NH][136]; // 4.3KB
  __shared__ float lsum[4][16];
  __shared__ unsigned last_flag;
  _Float16 (*c1s)[4][HIDD] = (_Float16 (*)[4][HIDD])pool;  // [qq][kyrow-local][f]
  float (*part)[4][NH][32] = (float (*)[4][NH][32])pool;   // [qq][wave][h][d]

  // ---- staging from f16 tables ----
  {
    int f0 = tid * 2;
    h2v ny2 = *(const h2v*)(ny16 + f0);
    h2v nx2 = *(const h2v*)(nx16 + f0);
    *(h2v*)&nwx[f0] = nx2;
    #pragma unroll
    for (int qq = 0; qq < 2; qq++){
      h2v a2 = *(const h2v*)(a16 + (q0+qq)*HIDD + f0);
      #pragma unroll
      for (int r = 0; r < 4; r++){
        _Float16 kyh = (_Float16)(((float)(kr*4 + r) + 0.5f) * (1.0f/32.0f));
        h2v ky2 = {kyh, kyh};
        *(h2v*)&c1s[qq][r][f0] = ny2 * ky2 + a2;    // v_pk_fma_f16
      }
    }
  }
  for (int e = tid; e < 512; e += 256){
    int r = e >> 6, c = e & 63;
    *(f16x8*)&w2l[r][c*8] = *(const f16x8*)(w216 + r*HIDD + c*8);
  }
  // masked q fragments: col n = query (n>>3), head (n&7)
  f16x8 qfrag = *(const f16x8*)(qb + (q0 + (n >> 3))*CDIM + (n & 7)*HD + qd*8);
  f16x8 qm[NH];
  #pragma unroll
  for (int h = 0; h < NH; h++){
    f16x8 z = {0,0,0,0,0,0,0,0};
    qm[h] = ((n & 7) == h) ? qfrag : z;
  }
  __syncthreads();

  const int kyrow = kr*4 + wave;          // global ky row (0..31)
  const int kbase = kyrow * 32;

  // ---- phase 1: logits for both queries ----
  f32x4 acc1[2] = {{0.f,0.f,0.f,0.f},{0.f,0.f,0.f,0.f}};
  #pragma unroll
  for (int t = 0; t < 2; t++){
    int k0 = kbase + t*16;
    #pragma unroll
    for (int h = 0; h < NH; h++){
      f16x8 af = *(const f16x8*)(kb + ((size_t)h*HWK + k0 + n)*HD + qd*8);
      acc1[t] = __builtin_amdgcn_mfma_f32_16x16x32_f16(af, qm[h], acc1[t], 0, 0, 0);
    }
  }

  // ---- phase 2: 4 chains accb[qq][t] += relu(c1_qq - wx*kx) @ W2^T ----
  _Float16 kxAh = (_Float16)(((float)n + 0.5f) * (1.0f/32.0f));
  _Float16 kxBh = (_Float16)(((float)n + 16.5f) * (1.0f/32.0f));
  f16x8 kxA8, kxB8, z8;
  #pragma unroll
  for (int j = 0; j < 8; j++){ kxA8[j] = kxAh; kxB8[j] = kxBh; z8[j] = (_Float16)0.f; }
  f32x4 accb[2][2];
  accb[0][0] = acc1[0]; accb[0][1] = acc1[1];
  accb[1][0] = acc1[0]; accb[1][1] = acc1[1];
  const _Float16* c1r0 = &c1s[0][wave][0];
  const _Float16* c1r1 = &c1s[1][wave][0];
  #pragma unroll 4
  for (int kc = 0; kc < 16; kc++){
    int f0 = kc*32 + qd*8;
    f16x8 c10 = *(const f16x8*)(c1r0 + f0);
    f16x8 c11 = *(const f16x8*)(c1r1 + f0);
    f16x8 wxv = *(const f16x8*)(&nwx[f0]);
    f16x8 bfr = *(const f16x8*)(&w2l[n & 7][f0]);
    #pragma unroll
    for (int t = 0; t < 2; t++){
      f16x8 kx8 = t ? kxB8 : kxA8;
      f16x8 e0 = __builtin_elementwise_max(wxv * kx8 + c10, z8);
      accb[0][t] = __builtin_amdgcn_mfma_f32_16x16x32_f16(e0, bfr, accb[0][t], 0, 0, 0);
      f16x8 e1 = __builtin_elementwise_max(wxv * kx8 + c11, z8);
      accb[1][t] = __builtin_amdgcn_mfma_f32_16x16x32_f16(e1, bfr, accb[1][t], 0, 0, 0);
    }
  }

  // ---- phase 3: exp (no max-subtract), pb f16, l partials ----
  int qsel = n >> 3, hsel = n & 7;
  float lacc = 0.f;
  #pragma unroll
  for (int t = 0; t < 2; t++){
    f32x4 a = qsel ? accb[1][t] : accb[0][t];
    float e0 = __expf(a[0]);
    float e1 = __expf(a[1]);
    float e2 = __expf(a[2]);
    float e3 = __expf(a[3]);
    uint2 p2;
    p2.x = pk_f16(e0, e1);
    p2.y = pk_f16(e2, e3);
    *(uint2*)&pb[qsel][hsel][wave*32 + t*16 + qd*4] = p2;
    float s = e0 + e1 + e2 + e3;
    s += __shfl_xor(s, 16);
    s += __shfl_xor(s, 32);
    lacc += s;
  }
  if (lane < 16) lsum[wave][lane] = lacc;

  // ---- phase 4: PV for both queries ----
  #pragma unroll
  for (int h = 0; h < NH; h++){
    int kl = wave*32 + qd*8;
    f16x8 pa = *(const f16x8*)&pb[n & 1][h][kl];
    f16x8 v0 = *(const f16x8*)(vt + ((size_t)(h*HD +      n))*HWK + kr*128 + kl);
    f16x8 v1 = *(const f16x8*)(vt + ((size_t)(h*HD + 16 + n))*HWK + kr*128 + kl);
    f32x4 o0 = {0.f,0.f,0.f,0.f}, o1 = {0.f,0.f,0.f,0.f};
    o0 = __builtin_amdgcn_mfma_f32_16x16x32_f16(pa, v0, o0, 0, 0, 0);
    o1 = __builtin_amdgcn_mfma_f32_16x16x32_f16(pa, v1, o1, 0, 0, 0);
    if (qd == 0){
      part[0][wave][h][n]      = o0[0];   // D row 0 = q0
      part[1][wave][h][n]      = o0[1];   // D row 1 = q1
      part[0][wave][h][16 + n] = o1[0];
      part[1][wave][h][16 + n] = o1[1];
    }
  }
  __syncthreads();

  // ---- combine waves, write partials for both queries ----
  {
    int h = tid >> 5, d = tid & 31;
    #pragma unroll
    for (int qq = 0; qq < 2; qq++){
      float s = part[qq][0][h][d] + part[qq][1][h][d]
              + part[qq][2][h][d] + part[qq][3][h][d];
      po[((size_t)kr*NQ + q0 + qq)*CDIM + tid] = s;
    }
    if (tid < 16){
      float s = lsum[0][tid] + lsum[1][tid] + lsum[2][tid] + lsum[3][tid];
      pl[((size_t)kr*NQ + q0 + (tid >> 3))*NH + (tid & 7)] = s;
    }
  }

  // ---- last-arrival inline output projection (no spin, no sleep) ----
  __threadfence();          // release: each thread's po/pl stores -> agent scope
  __syncthreads();          // all threads of the block have fenced
  if (tid == 0){
    unsigned prev = __hip_atomic_fetch_add(&qcnt[bid >> 3], 1u,
        __ATOMIC_ACQ_REL, __HIP_MEMORY_SCOPE_AGENT);
    last_flag = (prev == 7u) ? 1u : 0u;
  }
  __syncthreads();
  if (last_flag){
    __threadfence();        // acquire: drop stale cached po/pl lines
    dev_outproj(q0,     po, pl, Wo, bo, dout, pool);
    __syncthreads();
    dev_outproj(q0 + 1, po, pl, Wo, bo, dout, pool);
  }
}

extern "C" void kernel_launch(void* const* d_in, const int* in_sizes, int n_in,
                              void* d_out, int out_size, void* d_ws, size_t ws_size,
                              hipStream_t stream)
{
  const float* rq  = (const float*)d_in[0];
  const float* qp  = (const float*)d_in[1];
  const float* rp  = (const float*)d_in[2];
  const float* rs  = (const float*)d_in[3];
  const float* spe = (const float*)d_in[4];
  const float* Wq  = (const float*)d_in[5];
  const float* bq  = (const float*)d_in[6];
  const float* Wk  = (const float*)d_in[7];
  const float* bk  = (const float*)d_in[8];
  const float* Wv  = (const float*)d_in[9];
  const float* bv  = (const float*)d_in[10];
  const float* Wo  = (const float*)d_in[11];
  const float* bo  = (const float*)d_in[12];
  const float* W1  = (const float*)d_in[13];
  const float* b1  = (const float*)d_in[14];
  const float* W2  = (const float*)d_in[15];
  char* ws = (char*)d_ws;
  float* dout = (float*)d_out;

  // zero per-qpair arrival counters (ws is re-poisoned by the harness each iter)
  hipMemsetAsync(ws + QC_OFF, 0, 1024, stream);

  proj_kernel<<<912, 256, 0, stream>>>(rq, qp, rs, spe, Wq, bq, Wk, bk,
      Wv, bv, rp, W1, b1, W2, ws);
  fused_kernel<<<1200, 256, 0, stream>>>((const short*)(ws + A16_OFF),
      (const short*)(ws + NX_OFF), (const short*)(ws + NY_OFF),
      (const short*)(ws + W2_OFF), (const short*)(ws + QB_OFF),
      (const short*)(ws + KB_OFF), (const short*)(ws + VT_OFF),
      (float*)(ws + PO_OFF), (float*)(ws + PL_OFF),
      Wo, bo, dout, (unsigned*)(ws + QC_OFF));
}

// Round 6
// 196.248 us; speedup vs baseline: 2.9722x; 1.6264x over previous
//
#include <hip/hip_runtime.h>
#include <hip/hip_fp16.h>
#include <stdint.h>

#define NQ   300
#define CDIM 256
#define NH   8
#define HD   32
#define HWK  1024
#define HIDD 512

typedef __attribute__((ext_vector_type(8))) _Float16 f16x8;
typedef __attribute__((ext_vector_type(2))) _Float16 h2v;
typedef __attribute__((ext_vector_type(4))) float f32x4;

// ---- ws byte offsets ----
#define QB_OFF   0          // 300*256 f16 [q][c], scale folded
#define KB_OFF   153600     // 8*1024*32 f16 [h][k][d]
#define VT_OFF   677888     // [256 ch][1024 k] f16
#define A16_OFF  3736576    // [300][512] f16 a(q,f)
#define NX_OFF   4043776    // [512] f16 -wx
#define NY_OFF   4044800    // [512] f16 -wy
#define W2_OFF   4045824    // [8][512] f16 W2

__device__ __forceinline__ short f16b(float x){
  _Float16 h = (_Float16)x;
  return __builtin_bit_cast(short, h);
}

__device__ __forceinline__ uint32_t pk_f16(float a, float b){
  auto r = __builtin_amdgcn_cvt_pkrtz(a, b);
  return __builtin_bit_cast(uint32_t, r);
}

// ---------------- projection GEMMs + fused prep blocks ----------------
// bxid 0..293: tile = bxid>>1, half = bxid&1
//   tile 0-18  : q -> QB f16 (scaled)
//   tile 19-82 : k -> KB [h][k][d]
//   tile 83-146: v -> VT transposed
// bxid 294..911: prep path (f16 CPB tables), runs concurrently.
__global__ __launch_bounds__(256) void proj_kernel(
    const float* __restrict__ rq, const float* __restrict__ qp,
    const float* __restrict__ rs, const float* __restrict__ spe,
    const float* __restrict__ Wq, const float* __restrict__ bq,
    const float* __restrict__ Wk, const float* __restrict__ bk,
    const float* __restrict__ Wv, const float* __restrict__ bv,
    const float* __restrict__ refp, const float* __restrict__ W1,
    const float* __restrict__ b1, const float* __restrict__ W2,
    char* __restrict__ ws)
{
  int bxid = blockIdx.x;
  __shared__ __align__(16) float At[32][20];
  __shared__ float Wl[32][129];

  if (bxid >= 294){
    // ---- prep path ----
    int idx = (bxid - 294) * 256 + threadIdx.x;
    short* a16  = (short*)(ws + A16_OFF);
    short* nx16 = (short*)(ws + NX_OFF);
    short* ny16 = (short*)(ws + NY_OFF);
    short* w216 = (short*)(ws + W2_OFF);
    if (idx < NQ*HIDD){
      int q = idx >> 9, f = idx & 511;
      float2 w = ((const float2*)W1)[f];
      float a = fmaf(w.x, refp[2*q], fmaf(w.y, refp[2*q+1], b1[f]));
      a16[idx] = f16b(a);
    } else {
      int j = idx - NQ*HIDD;
      if (j < HIDD){
        float2 w = ((const float2*)W1)[j];
        nx16[j] = f16b(-w.x);
        ny16[j] = f16b(-w.y);
      } else if (j < HIDD + NH*HIDD){
        int e = j - HIDD;
        w216[e] = f16b(W2[e]);
      }
    }
    return;
  }

  int tile = bxid >> 1, half = bxid & 1;
  const float *in1, *in2, *W, *bias;
  int r0, M, mode;
  if (tile < 19){
    in1 = rq; in2 = qp; W = Wq; bias = bq; r0 = tile*16; M = NQ; mode = 0;
  } else if (tile < 83){
    in1 = rs; in2 = spe; W = Wk; bias = bk; r0 = (tile-19)*16; M = HWK; mode = 1;
  } else {
    in1 = rs; in2 = spe; W = Wv; bias = bv; r0 = (tile-83)*16; M = HWK; mode = 2;
  }
  int tid = threadIdx.x;
  int n_loc = tid & 127;
  int rg = tid >> 7;
  int n = half*128 + n_loc;
  float acc[8];
  float bv_ = bias[n];
  #pragma unroll
  for (int i=0;i<8;i++) acc[i] = bv_;

  for (int c0 = 0; c0 < CDIM; c0 += 32){
    __syncthreads();
    for (int e = tid; e < 512; e += 256){
      int r = e >> 5, c = e & 31;
      int gr = r0 + r; if (gr >= M) gr = M - 1;
      At[c][r] = in1[gr*CDIM + c0 + c] + in2[gr*CDIM + c0 + c];
    }
    for (int e = tid; e < 4096; e += 256){
      int c = e & 31, nn = e >> 5;
      Wl[c][nn] = W[(half*128 + nn)*CDIM + c0 + c];
    }
    __syncthreads();
    #pragma unroll
    for (int c = 0; c < 32; c++){
      float w = Wl[c][n_loc];
      const float4* ap = (const float4*)&At[c][rg*8];
      float4 a0 = ap[0], a1 = ap[1];
      acc[0] = fmaf(a0.x, w, acc[0]);
      acc[1] = fmaf(a0.y, w, acc[1]);
      acc[2] = fmaf(a0.z, w, acc[2]);
      acc[3] = fmaf(a0.w, w, acc[3]);
      acc[4] = fmaf(a1.x, w, acc[4]);
      acc[5] = fmaf(a1.y, w, acc[5]);
      acc[6] = fmaf(a1.z, w, acc[6]);
      acc[7] = fmaf(a1.w, w, acc[7]);
    }
  }

  if (mode == 0){
    short* qb = (short*)(ws + QB_OFF);
    const float s = 0.17677669529663687f;  // 1/sqrt(32)
    #pragma unroll
    for (int i=0;i<8;i++){
      int gr = r0 + rg*8 + i;
      if (gr < M) qb[gr*CDIM + n] = f16b(acc[i]*s);
    }
  } else if (mode == 1){
    short* kb = (short*)(ws + KB_OFF);
    int h = n >> 5, d = n & 31;
    #pragma unroll
    for (int i=0;i<8;i++){
      int gr = r0 + rg*8 + i;
      if (gr < M) kb[((size_t)h*HWK + gr)*HD + d] = f16b(acc[i]);
    }
  } else {
    short* vt = (short*)(ws + VT_OFF);
    uint32_t p[4];
    #pragma unroll
    for (int i=0;i<4;i++) p[i] = pk_f16(acc[2*i], acc[2*i+1]);
    *(uint4*)(vt + n*HWK + r0 + rg*8) = make_uint4(p[0], p[1], p[2], p[3]);
  }
}

// ---------------- fused2: one block per query pair, kr looped internally ----------------
// grid = 150. Per block: loop kr=0..7 over the verified round-2 unit (logits,
// CPB MLP, exp, PV), accumulate O in LDS + l in registers, then normalize and
// inline the output projection. No cross-block sync of any kind.
__global__ __launch_bounds__(256) void fused_kernel(
    const short* __restrict__ a16, const short* __restrict__ nx16,
    const short* __restrict__ ny16, const short* __restrict__ w216,
    const short* __restrict__ qb, const short* __restrict__ kb,
    const short* __restrict__ vt,
    const float* __restrict__ Wo, const float* __restrict__ bo,
    float* __restrict__ dout)
{
  int bid = blockIdx.x;
  int q0 = bid * 2;
  int tid = threadIdx.x, wave = tid >> 6, lane = tid & 63;
  int n = lane & 15, qd = lane >> 4;

  __shared__ __align__(16) _Float16 nwx[HIDD];      // 1KB
  __shared__ __align__(16) char pool[8192];         // c1s (ph1-2) / part (ph4)
  __shared__ __align__(16) _Float16 w2l[NH][520];   // 8.3KB
  __shared__ __align__(16) _Float16 pb[2][NH][136]; // 4.3KB
  __shared__ float lsum[4][16];
  __shared__ __align__(16) float o_acc[2][CDIM];    // 2KB O accumulator
  __shared__ float linv_s[16];
  _Float16 (*c1s)[4][HIDD] = (_Float16 (*)[4][HIDD])pool;  // [qq][kyrow-local][f]
  float (*part)[4][NH][32] = (float (*)[4][NH][32])pool;   // [qq][wave][h][d]

  // ---- hoisted per-block staging ----
  int f0 = tid * 2;
  h2v ny2 = *(const h2v*)(ny16 + f0);
  h2v nx2 = *(const h2v*)(nx16 + f0);
  *(h2v*)&nwx[f0] = nx2;
  h2v a2q[2];
  a2q[0] = *(const h2v*)(a16 + q0*HIDD + f0);
  a2q[1] = *(const h2v*)(a16 + (q0+1)*HIDD + f0);
  for (int e = tid; e < 512; e += 256){
    int r = e >> 6, c = e & 63;
    *(f16x8*)&w2l[r][c*8] = *(const f16x8*)(w216 + r*HIDD + c*8);
  }
  // masked q fragments: col n = query (n>>3), head (n&7)
  f16x8 qfrag = *(const f16x8*)(qb + (q0 + (n >> 3))*CDIM + (n & 7)*HD + qd*8);
  f16x8 qm[NH];
  #pragma unroll
  for (int h = 0; h < NH; h++){
    f16x8 z = {0,0,0,0,0,0,0,0};
    qm[h] = ((n & 7) == h) ? qfrag : z;
  }
  // x-coordinate constants
  _Float16 kxAh = (_Float16)(((float)n + 0.5f) * (1.0f/32.0f));
  _Float16 kxBh = (_Float16)(((float)n + 16.5f) * (1.0f/32.0f));
  f16x8 kxA8, kxB8, z8;
  #pragma unroll
  for (int j = 0; j < 8; j++){ kxA8[j] = kxAh; kxB8[j] = kxBh; z8[j] = (_Float16)0.f; }

  // zero O accumulator (each tid owns its own slots; read later by same tid
  // in combine-accumulate, so no extra sync needed beyond the loop's ones)
  o_acc[0][tid] = 0.f;
  o_acc[1][tid] = 0.f;

  float lacc = 0.f;     // per-thread exp-sum partial, accumulated over kr

  for (int kr = 0; kr < 8; kr++){
    // ---- stage c1s for this kr (pool was released by previous combine) ----
    #pragma unroll
    for (int r = 0; r < 4; r++){
      _Float16 kyh = (_Float16)(((float)(kr*4 + r) + 0.5f) * (1.0f/32.0f));
      h2v ky2 = {kyh, kyh};
      *(h2v*)&c1s[0][r][f0] = ny2 * ky2 + a2q[0];
      *(h2v*)&c1s[1][r][f0] = ny2 * ky2 + a2q[1];
    }
    __syncthreads();

    const int kyrow = kr*4 + wave;          // global ky row (0..31)
    const int kbase = kyrow * 32;

    // ---- phase 1: logits for both queries ----
    f32x4 acc1[2] = {{0.f,0.f,0.f,0.f},{0.f,0.f,0.f,0.f}};
    #pragma unroll
    for (int t = 0; t < 2; t++){
      int k0 = kbase + t*16;
      #pragma unroll
      for (int h = 0; h < NH; h++){
        f16x8 af = *(const f16x8*)(kb + ((size_t)h*HWK + k0 + n)*HD + qd*8);
        acc1[t] = __builtin_amdgcn_mfma_f32_16x16x32_f16(af, qm[h], acc1[t], 0, 0, 0);
      }
    }

    // ---- phase 2: 4 chains accb[qq][t] += relu(c1_qq - wx*kx) @ W2^T ----
    f32x4 accb[2][2];
    accb[0][0] = acc1[0]; accb[0][1] = acc1[1];
    accb[1][0] = acc1[0]; accb[1][1] = acc1[1];
    const _Float16* c1r0 = &c1s[0][wave][0];
    const _Float16* c1r1 = &c1s[1][wave][0];
    #pragma unroll 4
    for (int kc = 0; kc < 16; kc++){
      int ff = kc*32 + qd*8;
      f16x8 c10 = *(const f16x8*)(c1r0 + ff);
      f16x8 c11 = *(const f16x8*)(c1r1 + ff);
      f16x8 wxv = *(const f16x8*)(&nwx[ff]);
      f16x8 bfr = *(const f16x8*)(&w2l[n & 7][ff]);
      #pragma unroll
      for (int t = 0; t < 2; t++){
        f16x8 kx8 = t ? kxB8 : kxA8;
        f16x8 e0 = __builtin_elementwise_max(wxv * kx8 + c10, z8);
        accb[0][t] = __builtin_amdgcn_mfma_f32_16x16x32_f16(e0, bfr, accb[0][t], 0, 0, 0);
        f16x8 e1 = __builtin_elementwise_max(wxv * kx8 + c11, z8);
        accb[1][t] = __builtin_amdgcn_mfma_f32_16x16x32_f16(e1, bfr, accb[1][t], 0, 0, 0);
      }
    }

    // ---- phase 3: exp (no max-subtract), pb f16, l partial accumulate ----
    int qsel = n >> 3, hsel = n & 7;
    #pragma unroll
    for (int t = 0; t < 2; t++){
      f32x4 a = qsel ? accb[1][t] : accb[0][t];
      float e0 = __expf(a[0]);
      float e1 = __expf(a[1]);
      float e2 = __expf(a[2]);
      float e3 = __expf(a[3]);
      uint2 p2;
      p2.x = pk_f16(e0, e1);
      p2.y = pk_f16(e2, e3);
      *(uint2*)&pb[qsel][hsel][wave*32 + t*16 + qd*4] = p2;
      float s = e0 + e1 + e2 + e3;
      s += __shfl_xor(s, 16);
      s += __shfl_xor(s, 32);
      lacc += s;
    }

    // ---- phase 4: PV for both queries (pb slices are per-wave private) ----
    #pragma unroll
    for (int h = 0; h < NH; h++){
      int kl = wave*32 + qd*8;
      f16x8 pa = *(const f16x8*)&pb[n & 1][h][kl];
      f16x8 v0 = *(const f16x8*)(vt + ((size_t)(h*HD +      n))*HWK + kr*128 + kl);
      f16x8 v1 = *(const f16x8*)(vt + ((size_t)(h*HD + 16 + n))*HWK + kr*128 + kl);
      f32x4 o0 = {0.f,0.f,0.f,0.f}, o1 = {0.f,0.f,0.f,0.f};
      o0 = __builtin_amdgcn_mfma_f32_16x16x32_f16(pa, v0, o0, 0, 0, 0);
      o1 = __builtin_amdgcn_mfma_f32_16x16x32_f16(pa, v1, o1, 0, 0, 0);
      if (qd == 0){
        part[0][wave][h][n]      = o0[0];   // D row 0 = q0
        part[1][wave][h][n]      = o0[1];   // D row 1 = q1
        part[0][wave][h][16 + n] = o1[0];
        part[1][wave][h][16 + n] = o1[1];
      }
    }
    __syncthreads();

    // ---- combine waves into the per-block O accumulator ----
    {
      int h = tid >> 5, d = tid & 31;
      #pragma unroll
      for (int qq = 0; qq < 2; qq++){
        o_acc[qq][tid] += part[qq][0][h][d] + part[qq][1][h][d]
                        + part[qq][2][h][d] + part[qq][3][h][d];
      }
    }
    __syncthreads();   // release pool before next iteration's staging
  }

  // ---- final: l totals, normalize, inline output projection ----
  if (lane < 16) lsum[wave][lane] = lacc;   // lane = qsel*8 + hsel
  __syncthreads();
  if (tid < 16){
    float l = lsum[0][tid] + lsum[1][tid] + lsum[2][tid] + lsum[3][tid];
    linv_s[tid] = 1.0f / l;                 // tid = qq*8 + h
  }
  __syncthreads();
  o_acc[0][tid] *= linv_s[tid >> 5];
  o_acc[1][tid] *= linv_s[8 + (tid >> 5)];
  __syncthreads();

  const float4* wrow = (const float4*)(Wo + (size_t)tid*CDIM);
  const float4* av0 = (const float4*)&o_acc[0][0];
  const float4* av1 = (const float4*)&o_acc[1][0];
  float s0 = bo[tid], s1 = s0;
  #pragma unroll 8
  for (int c = 0; c < 64; c++){
    float4 w = wrow[c];
    float4 a0 = av0[c];
    float4 a1 = av1[c];
    s0 = fmaf(w.x,a0.x,fmaf(w.y,a0.y,fmaf(w.z,a0.z,fmaf(w.w,a0.w,s0))));
    s1 = fmaf(w.x,a1.x,fmaf(w.y,a1.y,fmaf(w.z,a1.z,fmaf(w.w,a1.w,s1))));
  }
  dout[(size_t)q0*CDIM + tid]       = s0;
  dout[(size_t)(q0+1)*CDIM + tid]   = s1;
}

extern "C" void kernel_launch(void* const* d_in, const int* in_sizes, int n_in,
                              void* d_out, int out_size, void* d_ws, size_t ws_size,
                              hipStream_t stream)
{
  const float* rq  = (const float*)d_in[0];
  const float* qp  = (const float*)d_in[1];
  const float* rp  = (const float*)d_in[2];
  const float* rs  = (const float*)d_in[3];
  const float* spe = (const float*)d_in[4];
  const float* Wq  = (const float*)d_in[5];
  const float* bq  = (const float*)d_in[6];
  const float* Wk  = (const float*)d_in[7];
  const float* bk  = (const float*)d_in[8];
  const float* Wv  = (const float*)d_in[9];
  const float* bv  = (const float*)d_in[10];
  const float* Wo  = (const float*)d_in[11];
  const float* bo  = (const float*)d_in[12];
  const float* W1  = (const float*)d_in[13];
  const float* b1  = (const float*)d_in[14];
  const float* W2  = (const float*)d_in[15];
  char* ws = (char*)d_ws;
  float* dout = (float*)d_out;

  proj_kernel<<<912, 256, 0, stream>>>(rq, qp, rs, spe, Wq, bq, Wk, bk,
      Wv, bv, rp, W1, b1, W2, ws);
  fused_kernel<<<150, 256, 0, stream>>>((const short*)(ws + A16_OFF),
      (const short*)(ws + NX_OFF), (const short*)(ws + NY_OFF),
      (const short*)(ws + W2_OFF), (const short*)(ws + QB_OFF),
      (const short*)(ws + KB_OFF), (const short*)(ws + VT_OFF),
      Wo, bo, dout);
}

// Round 7
// 169.048 us; speedup vs baseline: 3.4505x; 1.1609x over previous
//
#include <hip/hip_runtime.h>
#include <hip/hip_fp16.h>
#include <stdint.h>

#define NQ   300
#define CDIM 256
#define NH   8
#define HD   32
#define HWK  1024
#define HIDD 512

typedef __attribute__((ext_vector_type(8))) _Float16 f16x8;
typedef __attribute__((ext_vector_type(2))) _Float16 h2v;
typedef __attribute__((ext_vector_type(4))) float f32x4;

// ---- ws byte offsets ----
#define QB_OFF   0          // 300*256 f16 [q][c], scale folded
#define KB_OFF   153600     // 8*1024*32 f16 [h][k][d]
#define VT_OFF   677888     // [256 ch][1024 k] f16
#define A16_OFF  3736576    // [300][512] f16 a(q,f)
#define NX_OFF   4043776    // [512] f16 -wx
#define NY_OFF   4044800    // [512] f16 -wy
#define W2_OFF   4045824    // [8][512] f16 W2

__device__ __forceinline__ short f16b(float x){
  _Float16 h = (_Float16)x;
  return __builtin_bit_cast(short, h);
}

__device__ __forceinline__ uint32_t pk_f16(float a, float b){
  auto r = __builtin_amdgcn_cvt_pkrtz(a, b);
  return __builtin_bit_cast(uint32_t, r);
}

// ---------------- projection GEMMs + fused prep blocks ----------------
// bxid 0..293: tile = bxid>>1, half = bxid&1
//   tile 0-18  : q -> QB f16 (scaled)
//   tile 19-82 : k -> KB [h][k][d]
//   tile 83-146: v -> VT transposed
// bxid 294..911: prep path (f16 CPB tables), runs concurrently.
__global__ __launch_bounds__(256) void proj_kernel(
    const float* __restrict__ rq, const float* __restrict__ qp,
    const float* __restrict__ rs, const float* __restrict__ spe,
    const float* __restrict__ Wq, const float* __restrict__ bq,
    const float* __restrict__ Wk, const float* __restrict__ bk,
    const float* __restrict__ Wv, const float* __restrict__ bv,
    const float* __restrict__ refp, const float* __restrict__ W1,
    const float* __restrict__ b1, const float* __restrict__ W2,
    char* __restrict__ ws)
{
  int bxid = blockIdx.x;
  __shared__ __align__(16) float At[32][20];
  __shared__ float Wl[32][129];

  if (bxid >= 294){
    // ---- prep path ----
    int idx = (bxid - 294) * 256 + threadIdx.x;
    short* a16  = (short*)(ws + A16_OFF);
    short* nx16 = (short*)(ws + NX_OFF);
    short* ny16 = (short*)(ws + NY_OFF);
    short* w216 = (short*)(ws + W2_OFF);
    if (idx < NQ*HIDD){
      int q = idx >> 9, f = idx & 511;
      float2 w = ((const float2*)W1)[f];
      float a = fmaf(w.x, refp[2*q], fmaf(w.y, refp[2*q+1], b1[f]));
      a16[idx] = f16b(a);
    } else {
      int j = idx - NQ*HIDD;
      if (j < HIDD){
        float2 w = ((const float2*)W1)[j];
        nx16[j] = f16b(-w.x);
        ny16[j] = f16b(-w.y);
      } else if (j < HIDD + NH*HIDD){
        int e = j - HIDD;
        w216[e] = f16b(W2[e]);
      }
    }
    return;
  }

  int tile = bxid >> 1, half = bxid & 1;
  const float *in1, *in2, *W, *bias;
  int r0, M, mode;
  if (tile < 19){
    in1 = rq; in2 = qp; W = Wq; bias = bq; r0 = tile*16; M = NQ; mode = 0;
  } else if (tile < 83){
    in1 = rs; in2 = spe; W = Wk; bias = bk; r0 = (tile-19)*16; M = HWK; mode = 1;
  } else {
    in1 = rs; in2 = spe; W = Wv; bias = bv; r0 = (tile-83)*16; M = HWK; mode = 2;
  }
  int tid = threadIdx.x;
  int n_loc = tid & 127;
  int rg = tid >> 7;
  int n = half*128 + n_loc;
  float acc[8];
  float bv_ = bias[n];
  #pragma unroll
  for (int i=0;i<8;i++) acc[i] = bv_;

  for (int c0 = 0; c0 < CDIM; c0 += 32){
    __syncthreads();
    for (int e = tid; e < 512; e += 256){
      int r = e >> 5, c = e & 31;
      int gr = r0 + r; if (gr >= M) gr = M - 1;
      At[c][r] = in1[gr*CDIM + c0 + c] + in2[gr*CDIM + c0 + c];
    }
    for (int e = tid; e < 4096; e += 256){
      int c = e & 31, nn = e >> 5;
      Wl[c][nn] = W[(half*128 + nn)*CDIM + c0 + c];
    }
    __syncthreads();
    #pragma unroll
    for (int c = 0; c < 32; c++){
      float w = Wl[c][n_loc];
      const float4* ap = (const float4*)&At[c][rg*8];
      float4 a0 = ap[0], a1 = ap[1];
      acc[0] = fmaf(a0.x, w, acc[0]);
      acc[1] = fmaf(a0.y, w, acc[1]);
      acc[2] = fmaf(a0.z, w, acc[2]);
      acc[3] = fmaf(a0.w, w, acc[3]);
      acc[4] = fmaf(a1.x, w, acc[4]);
      acc[5] = fmaf(a1.y, w, acc[5]);
      acc[6] = fmaf(a1.z, w, acc[6]);
      acc[7] = fmaf(a1.w, w, acc[7]);
    }
  }

  if (mode == 0){
    short* qb = (short*)(ws + QB_OFF);
    const float s = 0.17677669529663687f;  // 1/sqrt(32)
    #pragma unroll
    for (int i=0;i<8;i++){
      int gr = r0 + rg*8 + i;
      if (gr < M) qb[gr*CDIM + n] = f16b(acc[i]*s);
    }
  } else if (mode == 1){
    short* kb = (short*)(ws + KB_OFF);
    int h = n >> 5, d = n & 31;
    #pragma unroll
    for (int i=0;i<8;i++){
      int gr = r0 + rg*8 + i;
      if (gr < M) kb[((size_t)h*HWK + gr)*HD + d] = f16b(acc[i]);
    }
  } else {
    short* vt = (short*)(ws + VT_OFF);
    uint32_t p[4];
    #pragma unroll
    for (int i=0;i<4;i++) p[i] = pk_f16(acc[2*i], acc[2*i+1]);
    *(uint4*)(vt + n*HWK + r0 + rg*8) = make_uint4(p[0], p[1], p[2], p[3]);
  }
}

// ---------------- fused3: one block per query pair, 8 waves, 2 kr groups ----------------
// grid = 150, 512 threads. Group g (waves 4g..4g+3) processes kr = 2*kri+g for
// kri = 0..3: half the serial depth of round 6, 2 waves/SIMD instead of 1.
// All math identical to the verified round-2 unit; per-group LDS copies.
__global__ __launch_bounds__(512) void fused_kernel(
    const short* __restrict__ a16, const short* __restrict__ nx16,
    const short* __restrict__ ny16, const short* __restrict__ w216,
    const short* __restrict__ qb, const short* __restrict__ kb,
    const short* __restrict__ vt,
    const float* __restrict__ Wo, const float* __restrict__ bo,
    float* __restrict__ dout)
{
  int bid = blockIdx.x;
  int q0 = bid * 2;
  int tid = threadIdx.x;
  int grp = tid >> 8;            // 0/1: kr parity group
  int tid_l = tid & 255;         // local id within group
  int wv = (tid >> 6) & 3;       // wave within group
  int lane = tid & 63;
  int n = lane & 15, qd = lane >> 4;

  __shared__ __align__(16) _Float16 nwx[HIDD];          // 1KB
  __shared__ __align__(16) char pool[2][8192];          // per-group c1s / part
  __shared__ __align__(16) _Float16 w2l[NH][520];       // 8.3KB
  __shared__ __align__(16) _Float16 pb[2][2][NH][136];  // 8.7KB, per-group
  __shared__ float lsum[8][16];                         // per-wave l partials
  __shared__ __align__(16) float o_acc[2][2][CDIM];     // [grp][qq][c], 4KB
  __shared__ float linv_s[16];

  _Float16 (*c1s)[4][HIDD] = (_Float16 (*)[4][HIDD])pool[grp];  // [qq][row][f]
  float (*part)[4][NH][32] = (float (*)[4][NH][32])pool[grp];   // [qq][wv][h][d]

  // ---- hoisted per-block staging ----
  int f0 = tid_l * 2;
  h2v ny2 = *(const h2v*)(ny16 + f0);
  h2v a2q[2];
  a2q[0] = *(const h2v*)(a16 + q0*HIDD + f0);
  a2q[1] = *(const h2v*)(a16 + (q0+1)*HIDD + f0);
  if (grp == 0){
    h2v nx2 = *(const h2v*)(nx16 + f0);
    *(h2v*)&nwx[f0] = nx2;
  }
  {
    int r = tid >> 6, c = tid & 63;   // 512 threads cover 8*64 chunks
    *(f16x8*)&w2l[r][c*8] = *(const f16x8*)(w216 + r*HIDD + c*8);
  }
  // masked q fragments: col n = query (n>>3), head (n&7)
  f16x8 qfrag = *(const f16x8*)(qb + (q0 + (n >> 3))*CDIM + (n & 7)*HD + qd*8);
  f16x8 qm[NH];
  #pragma unroll
  for (int h = 0; h < NH; h++){
    f16x8 z = {0,0,0,0,0,0,0,0};
    qm[h] = ((n & 7) == h) ? qfrag : z;
  }
  // x-coordinate constants
  _Float16 kxAh = (_Float16)(((float)n + 0.5f) * (1.0f/32.0f));
  _Float16 kxBh = (_Float16)(((float)n + 16.5f) * (1.0f/32.0f));
  f16x8 kxA8, kxB8, z8;
  #pragma unroll
  for (int j = 0; j < 8; j++){ kxA8[j] = kxAh; kxB8[j] = kxBh; z8[j] = (_Float16)0.f; }

  o_acc[grp][0][tid_l] = 0.f;
  o_acc[grp][1][tid_l] = 0.f;

  float lacc = 0.f;     // per-thread exp-sum partial over this group's kr set

  for (int kri = 0; kri < 4; kri++){
    const int kr = kri*2 + grp;

    // ---- stage c1s for this group's kr ----
    #pragma unroll
    for (int r = 0; r < 4; r++){
      _Float16 kyh = (_Float16)(((float)(kr*4 + r) + 0.5f) * (1.0f/32.0f));
      h2v ky2 = {kyh, kyh};
      *(h2v*)&c1s[0][r][f0] = ny2 * ky2 + a2q[0];
      *(h2v*)&c1s[1][r][f0] = ny2 * ky2 + a2q[1];
    }
    __syncthreads();

    const int kyrow = kr*4 + wv;          // global ky row (0..31)
    const int kbase = kyrow * 32;

    // ---- phase 1: logits for both queries ----
    f32x4 acc1[2] = {{0.f,0.f,0.f,0.f},{0.f,0.f,0.f,0.f}};
    #pragma unroll
    for (int t = 0; t < 2; t++){
      int k0 = kbase + t*16;
      #pragma unroll
      for (int h = 0; h < NH; h++){
        f16x8 af = *(const f16x8*)(kb + ((size_t)h*HWK + k0 + n)*HD + qd*8);
        acc1[t] = __builtin_amdgcn_mfma_f32_16x16x32_f16(af, qm[h], acc1[t], 0, 0, 0);
      }
    }

    // ---- phase 2: 4 chains accb[qq][t] += relu(c1_qq - wx*kx) @ W2^T ----
    f32x4 accb[2][2];
    accb[0][0] = acc1[0]; accb[0][1] = acc1[1];
    accb[1][0] = acc1[0]; accb[1][1] = acc1[1];
    const _Float16* c1r0 = &c1s[0][wv][0];
    const _Float16* c1r1 = &c1s[1][wv][0];
    #pragma unroll 4
    for (int kc = 0; kc < 16; kc++){
      int ff = kc*32 + qd*8;
      f16x8 c10 = *(const f16x8*)(c1r0 + ff);
      f16x8 c11 = *(const f16x8*)(c1r1 + ff);
      f16x8 wxv = *(const f16x8*)(&nwx[ff]);
      f16x8 bfr = *(const f16x8*)(&w2l[n & 7][ff]);
      #pragma unroll
      for (int t = 0; t < 2; t++){
        f16x8 kx8 = t ? kxB8 : kxA8;
        f16x8 e0 = __builtin_elementwise_max(wxv * kx8 + c10, z8);
        accb[0][t] = __builtin_amdgcn_mfma_f32_16x16x32_f16(e0, bfr, accb[0][t], 0, 0, 0);
        f16x8 e1 = __builtin_elementwise_max(wxv * kx8 + c11, z8);
        accb[1][t] = __builtin_amdgcn_mfma_f32_16x16x32_f16(e1, bfr, accb[1][t], 0, 0, 0);
      }
    }

    // ---- phase 3: exp (no max-subtract), pb f16, l partial accumulate ----
    int qsel = n >> 3, hsel = n & 7;
    #pragma unroll
    for (int t = 0; t < 2; t++){
      f32x4 a = qsel ? accb[1][t] : accb[0][t];
      float e0 = __expf(a[0]);
      float e1 = __expf(a[1]);
      float e2 = __expf(a[2]);
      float e3 = __expf(a[3]);
      uint2 p2;
      p2.x = pk_f16(e0, e1);
      p2.y = pk_f16(e2, e3);
      *(uint2*)&pb[grp][qsel][hsel][wv*32 + t*16 + qd*4] = p2;
      float s = e0 + e1 + e2 + e3;
      s += __shfl_xor(s, 16);
      s += __shfl_xor(s, 32);
      lacc += s;
    }

    // ---- phase 4: PV for both queries (pb slices are per-wave private) ----
    #pragma unroll
    for (int h = 0; h < NH; h++){
      int kl = wv*32 + qd*8;
      f16x8 pa = *(const f16x8*)&pb[grp][n & 1][h][kl];
      f16x8 v0 = *(const f16x8*)(vt + ((size_t)(h*HD +      n))*HWK + kr*128 + kl);
      f16x8 v1 = *(const f16x8*)(vt + ((size_t)(h*HD + 16 + n))*HWK + kr*128 + kl);
      f32x4 o0 = {0.f,0.f,0.f,0.f}, o1 = {0.f,0.f,0.f,0.f};
      o0 = __builtin_amdgcn_mfma_f32_16x16x32_f16(pa, v0, o0, 0, 0, 0);
      o1 = __builtin_amdgcn_mfma_f32_16x16x32_f16(pa, v1, o1, 0, 0, 0);
      if (qd == 0){
        part[0][wv][h][n]      = o0[0];   // D row 0 = q0
        part[1][wv][h][n]      = o0[1];   // D row 1 = q1
        part[0][wv][h][16 + n] = o1[0];
        part[1][wv][h][16 + n] = o1[1];
      }
    }
    __syncthreads();

    // ---- combine this group's waves into the group O accumulator ----
    {
      int h = tid_l >> 5, d = tid_l & 31;
      #pragma unroll
      for (int qq = 0; qq < 2; qq++){
        o_acc[grp][qq][tid_l] += part[qq][0][h][d] + part[qq][1][h][d]
                               + part[qq][2][h][d] + part[qq][3][h][d];
      }
    }
    __syncthreads();   // release pool before next iteration's staging
  }

  // ---- final: l totals, merge groups, normalize, inline output projection ----
  if (lane < 16) lsum[grp*4 + wv][lane] = lacc;   // lane = qsel*8 + hsel
  __syncthreads();
  if (tid < 16){
    float l = lsum[0][tid] + lsum[1][tid] + lsum[2][tid] + lsum[3][tid]
            + lsum[4][tid] + lsum[5][tid] + lsum[6][tid] + lsum[7][tid];
    linv_s[tid] = 1.0f / l;                       // tid = qq*8 + h
  }
  __syncthreads();
  // group g owns query q0+g from here on
  {
    float v = (o_acc[0][grp][tid_l] + o_acc[1][grp][tid_l])
            * linv_s[grp*8 + (tid_l >> 5)];
    o_acc[0][grp][tid_l] = v;
  }
  __syncthreads();

  const float4* wrow = (const float4*)(Wo + (size_t)tid_l*CDIM);
  const float4* av = (const float4*)&o_acc[0][grp][0];
  float s0 = bo[tid_l], s1 = 0.f, s2 = 0.f, s3 = 0.f;
  #pragma unroll 4
  for (int c = 0; c < 64; c += 4){
    float4 w0 = wrow[c+0], a0 = av[c+0];
    float4 w1 = wrow[c+1], a1 = av[c+1];
    float4 w2 = wrow[c+2], a2 = av[c+2];
    float4 w3 = wrow[c+3], a3 = av[c+3];
    s0 = fmaf(w0.x,a0.x,fmaf(w0.y,a0.y,fmaf(w0.z,a0.z,fmaf(w0.w,a0.w,s0))));
    s1 = fmaf(w1.x,a1.x,fmaf(w1.y,a1.y,fmaf(w1.z,a1.z,fmaf(w1.w,a1.w,s1))));
    s2 = fmaf(w2.x,a2.x,fmaf(w2.y,a2.y,fmaf(w2.z,a2.z,fmaf(w2.w,a2.w,s2))));
    s3 = fmaf(w3.x,a3.x,fmaf(w3.y,a3.y,fmaf(w3.z,a3.z,fmaf(w3.w,a3.w,s3))));
  }
  dout[(size_t)(q0 + grp)*CDIM + tid_l] = s0 + s1 + s2 + s3;
}

extern "C" void kernel_launch(void* const* d_in, const int* in_sizes, int n_in,
                              void* d_out, int out_size, void* d_ws, size_t ws_size,
                              hipStream_t stream)
{
  const float* rq  = (const float*)d_in[0];
  const float* qp  = (const float*)d_in[1];
  const float* rp  = (const float*)d_in[2];
  const float* rs  = (const float*)d_in[3];
  const float* spe = (const float*)d_in[4];
  const float* Wq  = (const float*)d_in[5];
  const float* bq  = (const float*)d_in[6];
  const float* Wk  = (const float*)d_in[7];
  const float* bk  = (const float*)d_in[8];
  const float* Wv  = (const float*)d_in[9];
  const float* bv  = (const float*)d_in[10];
  const float* Wo  = (const float*)d_in[11];
  const float* bo  = (const float*)d_in[12];
  const float* W1  = (const float*)d_in[13];
  const float* b1  = (const float*)d_in[14];
  const float* W2  = (const float*)d_in[15];
  char* ws = (char*)d_ws;
  float* dout = (float*)d_out;

  proj_kernel<<<912, 256, 0, stream>>>(rq, qp, rs, spe, Wq, bq, Wk, bk,
      Wv, bv, rp, W1, b1, W2, ws);
  fused_kernel<<<150, 512, 0, stream>>>((const short*)(ws + A16_OFF),
      (const short*)(ws + NX_OFF), (const short*)(ws + NY_OFF),
      (const short*)(ws + W2_OFF), (const short*)(ws + QB_OFF),
      (const short*)(ws + KB_OFF), (const short*)(ws + VT_OFF),
      Wo, bo, dout);
}

// Round 8
// 159.210 us; speedup vs baseline: 3.6637x; 1.0618x over previous
//
#include <hip/hip_runtime.h>
#include <hip/hip_fp16.h>
#include <stdint.h>

#define NQ   300
#define CDIM 256
#define NH   8
#define HD   32
#define HWK  1024
#define HIDD 512

typedef __attribute__((ext_vector_type(8))) _Float16 f16x8;
typedef __attribute__((ext_vector_type(2))) _Float16 h2v;
typedef __attribute__((ext_vector_type(4))) float f32x4;

// ---- ws byte offsets ----
#define QB_OFF   0          // 300*256 f16 [q][c], scale folded
#define KB_OFF   153600     // 8*1024*32 f16 [h][k][d]
#define VT_OFF   677888     // [256 ch][1024 k] f16
#define PO_OFF   1202176    // [8 kr][300 q][256 c] f32 partial O
#define PL_OFF   3659776    // [8 kr][300 q][8 h] f32 partial exp-sums
#define A16_OFF  3736576    // [300][512] f16 a(q,f)
#define NX_OFF   4043776    // [512] f16 -wx
#define NY_OFF   4044800    // [512] f16 -wy
#define W2_OFF   4045824    // [8][512] f16 W2

__device__ __forceinline__ short f16b(float x){
  _Float16 h = (_Float16)x;
  return __builtin_bit_cast(short, h);
}

__device__ __forceinline__ uint32_t pk_f16(float a, float b){
  auto r = __builtin_amdgcn_cvt_pkrtz(a, b);
  return __builtin_bit_cast(uint32_t, r);
}

// ---------------- projection GEMMs + fused prep blocks ----------------
// bxid 0..293: tile = bxid>>1, half = bxid&1
//   tile 0-18  : q -> QB f16 (scaled)
//   tile 19-82 : k -> KB [h][k][d]
//   tile 83-146: v -> VT transposed
// bxid 294..911: prep path (f16 CPB tables), runs concurrently.
__global__ __launch_bounds__(256) void proj_kernel(
    const float* __restrict__ rq, const float* __restrict__ qp,
    const float* __restrict__ rs, const float* __restrict__ spe,
    const float* __restrict__ Wq, const float* __restrict__ bq,
    const float* __restrict__ Wk, const float* __restrict__ bk,
    const float* __restrict__ Wv, const float* __restrict__ bv,
    const float* __restrict__ refp, const float* __restrict__ W1,
    const float* __restrict__ b1, const float* __restrict__ W2,
    char* __restrict__ ws)
{
  int bxid = blockIdx.x;
  __shared__ __align__(16) float At[32][20];
  __shared__ float Wl[32][129];

  if (bxid >= 294){
    // ---- prep path ----
    int idx = (bxid - 294) * 256 + threadIdx.x;
    short* a16  = (short*)(ws + A16_OFF);
    short* nx16 = (short*)(ws + NX_OFF);
    short* ny16 = (short*)(ws + NY_OFF);
    short* w216 = (short*)(ws + W2_OFF);
    if (idx < NQ*HIDD){
      int q = idx >> 9, f = idx & 511;
      float2 w = ((const float2*)W1)[f];
      float a = fmaf(w.x, refp[2*q], fmaf(w.y, refp[2*q+1], b1[f]));
      a16[idx] = f16b(a);
    } else {
      int j = idx - NQ*HIDD;
      if (j < HIDD){
        float2 w = ((const float2*)W1)[j];
        nx16[j] = f16b(-w.x);
        ny16[j] = f16b(-w.y);
      } else if (j < HIDD + NH*HIDD){
        int e = j - HIDD;
        w216[e] = f16b(W2[e]);
      }
    }
    return;
  }

  int tile = bxid >> 1, half = bxid & 1;
  const float *in1, *in2, *W, *bias;
  int r0, M, mode;
  if (tile < 19){
    in1 = rq; in2 = qp; W = Wq; bias = bq; r0 = tile*16; M = NQ; mode = 0;
  } else if (tile < 83){
    in1 = rs; in2 = spe; W = Wk; bias = bk; r0 = (tile-19)*16; M = HWK; mode = 1;
  } else {
    in1 = rs; in2 = spe; W = Wv; bias = bv; r0 = (tile-83)*16; M = HWK; mode = 2;
  }
  int tid = threadIdx.x;
  int n_loc = tid & 127;
  int rg = tid >> 7;
  int n = half*128 + n_loc;
  float acc[8];
  float bv_ = bias[n];
  #pragma unroll
  for (int i=0;i<8;i++) acc[i] = bv_;

  for (int c0 = 0; c0 < CDIM; c0 += 32){
    __syncthreads();
    for (int e = tid; e < 512; e += 256){
      int r = e >> 5, c = e & 31;
      int gr = r0 + r; if (gr >= M) gr = M - 1;
      At[c][r] = in1[gr*CDIM + c0 + c] + in2[gr*CDIM + c0 + c];
    }
    for (int e = tid; e < 4096; e += 256){
      int c = e & 31, nn = e >> 5;
      Wl[c][nn] = W[(half*128 + nn)*CDIM + c0 + c];
    }
    __syncthreads();
    #pragma unroll
    for (int c = 0; c < 32; c++){
      float w = Wl[c][n_loc];
      const float4* ap = (const float4*)&At[c][rg*8];
      float4 a0 = ap[0], a1 = ap[1];
      acc[0] = fmaf(a0.x, w, acc[0]);
      acc[1] = fmaf(a0.y, w, acc[1]);
      acc[2] = fmaf(a0.z, w, acc[2]);
      acc[3] = fmaf(a0.w, w, acc[3]);
      acc[4] = fmaf(a1.x, w, acc[4]);
      acc[5] = fmaf(a1.y, w, acc[5]);
      acc[6] = fmaf(a1.z, w, acc[6]);
      acc[7] = fmaf(a1.w, w, acc[7]);
    }
  }

  if (mode == 0){
    short* qb = (short*)(ws + QB_OFF);
    const float s = 0.17677669529663687f;  // 1/sqrt(32)
    #pragma unroll
    for (int i=0;i<8;i++){
      int gr = r0 + rg*8 + i;
      if (gr < M) qb[gr*CDIM + n] = f16b(acc[i]*s);
    }
  } else if (mode == 1){
    short* kb = (short*)(ws + KB_OFF);
    int h = n >> 5, d = n & 31;
    #pragma unroll
    for (int i=0;i<8;i++){
      int gr = r0 + rg*8 + i;
      if (gr < M) kb[((size_t)h*HWK + gr)*HD + d] = f16b(acc[i]);
    }
  } else {
    short* vt = (short*)(ws + VT_OFF);
    uint32_t p[4];
    #pragma unroll
    for (int i=0;i<4;i++) p[i] = pk_f16(acc[2*i], acc[2*i+1]);
    *(uint4*)(vt + n*HWK + r0 + rg*8) = make_uint4(p[0], p[1], p[2], p[3]);
  }
}

// ---------------- fused: ONE query per block, 8 kr slabs -> grid 2400 ----------------
// q = bid>>3, kr = bid&7. 4 waves; wave owns one kyrow of the 128-k slab.
// Same verified unit arithmetic as round 2, q1 path removed; full occupancy
// (8 blocks/CU under __launch_bounds__(256,8), LDS 15.9KB).
__global__ __launch_bounds__(256, 8) void fused_kernel(
    const short* __restrict__ a16, const short* __restrict__ nx16,
    const short* __restrict__ ny16, const short* __restrict__ w216,
    const short* __restrict__ qb, const short* __restrict__ kb,
    const short* __restrict__ vt, float* __restrict__ po,
    float* __restrict__ pl)
{
  int bid = blockIdx.x;
  int q = bid >> 3, kr = bid & 7;
  int tid = threadIdx.x, wave = tid >> 6, lane = tid & 63;
  int n = lane & 15, qd = lane >> 4;

  __shared__ __align__(16) _Float16 nwx[HIDD];      // 1KB
  __shared__ __align__(16) char pool[4096];         // c1s (ph1-2) / part (ph4), per-wave
  __shared__ __align__(16) _Float16 w2l[NH][520];   // 8.3KB
  __shared__ __align__(16) _Float16 pb[NH][136];    // 2.2KB
  __shared__ float lsum[4][16];
  _Float16 (*c1s)[HIDD] = (_Float16 (*)[HIDD])pool;    // [kyrow-local][f]
  float (*part)[NH][32] = (float (*)[NH][32])pool;     // [wave][h][d] — same region map

  // ---- staging from f16 tables ----
  {
    int f0 = tid * 2;
    h2v ny2 = *(const h2v*)(ny16 + f0);
    h2v nx2 = *(const h2v*)(nx16 + f0);
    *(h2v*)&nwx[f0] = nx2;
    h2v a2 = *(const h2v*)(a16 + q*HIDD + f0);
    #pragma unroll
    for (int r = 0; r < 4; r++){
      _Float16 kyh = (_Float16)(((float)(kr*4 + r) + 0.5f) * (1.0f/32.0f));
      h2v ky2 = {kyh, kyh};
      *(h2v*)&c1s[r][f0] = ny2 * ky2 + a2;    // v_pk_fma_f16
    }
  }
  for (int e = tid; e < 512; e += 256){
    int r = e >> 6, c = e & 63;
    *(f16x8*)&w2l[r][c*8] = *(const f16x8*)(w216 + r*HIDD + c*8);
  }
  // q fragment: head = n&7 (cols 8-15 masked to zero -> duplicate-free logits)
  f16x8 qfrag = *(const f16x8*)(qb + q*CDIM + (n & 7)*HD + qd*8);
  f16x8 z8f;
  #pragma unroll
  for (int j = 0; j < 8; j++) z8f[j] = (_Float16)0.f;
  __syncthreads();

  const int kyrow = kr*4 + wave;          // global ky row (0..31)
  const int kbase = kyrow * 32;

  // ---- phase 1: logits. h outer, t inner so the masked B frag is transient ----
  f32x4 acc1[2] = {{0.f,0.f,0.f,0.f},{0.f,0.f,0.f,0.f}};
  #pragma unroll
  for (int h = 0; h < NH; h++){
    f16x8 bq8 = ((n & 7) == h && n < 8) ? qfrag : z8f;
    #pragma unroll
    for (int t = 0; t < 2; t++){
      int k0 = kbase + t*16;
      f16x8 af = *(const f16x8*)(kb + ((size_t)h*HWK + k0 + n)*HD + qd*8);
      acc1[t] = __builtin_amdgcn_mfma_f32_16x16x32_f16(af, bq8, acc1[t], 0, 0, 0);
    }
  }

  // ---- phase 2: 2 chains accb[t] += relu(c1 - wx*kx) @ W2^T ----
  _Float16 kxAh = (_Float16)(((float)n + 0.5f) * (1.0f/32.0f));
  _Float16 kxBh = (_Float16)(((float)n + 16.5f) * (1.0f/32.0f));
  f16x8 kxA8, kxB8;
  #pragma unroll
  for (int j = 0; j < 8; j++){ kxA8[j] = kxAh; kxB8[j] = kxBh; }
  f32x4 accb[2];
  accb[0] = acc1[0]; accb[1] = acc1[1];
  const _Float16* c1r = &c1s[wave][0];
  #pragma unroll 4
  for (int kc = 0; kc < 16; kc++){
    int ff = kc*32 + qd*8;
    f16x8 c10 = *(const f16x8*)(c1r + ff);
    f16x8 wxv = *(const f16x8*)(&nwx[ff]);
    f16x8 bfr = *(const f16x8*)(&w2l[n & 7][ff]);
    #pragma unroll
    for (int t = 0; t < 2; t++){
      f16x8 kx8 = t ? kxB8 : kxA8;
      f16x8 e0 = __builtin_elementwise_max(wxv * kx8 + c10, z8f);
      accb[t] = __builtin_amdgcn_mfma_f32_16x16x32_f16(e0, bfr, accb[t], 0, 0, 0);
    }
  }

  // ---- phase 3: exp (no max-subtract), pb f16, l partials; valid cols n<8 ----
  float lacc = 0.f;
  #pragma unroll
  for (int t = 0; t < 2; t++){
    f32x4 a = accb[t];
    float e0 = __expf(a[0]);
    float e1 = __expf(a[1]);
    float e2 = __expf(a[2]);
    float e3 = __expf(a[3]);
    uint2 p2;
    p2.x = pk_f16(e0, e1);
    p2.y = pk_f16(e2, e3);
    float s = e0 + e1 + e2 + e3;
    s += __shfl_xor(s, 16);       // qd-reduce: lane^16/^32 keep the same n
    s += __shfl_xor(s, 32);
    if (n < 8){
      *(uint2*)&pb[n][wave*32 + t*16 + qd*4] = p2;
      lacc += s;
    }
  }
  if (lane < 8) lsum[wave][lane] = lacc;

  // ---- phase 4: PV (each wave consumes only its own pb k-chunk) ----
  #pragma unroll
  for (int h = 0; h < NH; h++){
    int kl = wave*32 + qd*8;
    f16x8 pa = *(const f16x8*)&pb[h][kl];
    f16x8 v0 = *(const f16x8*)(vt + ((size_t)(h*HD +      n))*HWK + kr*128 + kl);
    f16x8 v1 = *(const f16x8*)(vt + ((size_t)(h*HD + 16 + n))*HWK + kr*128 + kl);
    f32x4 o0 = {0.f,0.f,0.f,0.f}, o1 = {0.f,0.f,0.f,0.f};
    o0 = __builtin_amdgcn_mfma_f32_16x16x32_f16(pa, v0, o0, 0, 0, 0);
    o1 = __builtin_amdgcn_mfma_f32_16x16x32_f16(pa, v1, o1, 0, 0, 0);
    if (qd == 0){
      part[wave][h][n]      = o0[0];   // D row 0 = this query
      part[wave][h][16 + n] = o1[0];
    }
  }
  __syncthreads();

  // ---- combine waves, write partials ----
  {
    int h = tid >> 5, d = tid & 31;
    float s = part[0][h][d] + part[1][h][d] + part[2][h][d] + part[3][h][d];
    po[((size_t)kr*NQ + q)*CDIM + tid] = s;
    if (tid < 8){
      float l = lsum[0][tid] + lsum[1][tid] + lsum[2][tid] + lsum[3][tid];
      pl[((size_t)kr*NQ + q)*NH + tid] = l;
    }
  }
}

// ---------------- output projection: one block per query row (round-2 verified) ----------------
__global__ __launch_bounds__(256) void outproj_kernel(
    const float* __restrict__ po, const float* __restrict__ pl,
    const float* __restrict__ Wo, const float* __restrict__ bo,
    float* __restrict__ dout)
{
  int q = blockIdx.x;
  int tid = threadIdx.x;
  __shared__ __align__(16) float a_lds[CDIM];
  __shared__ float linv[NH];

  float s = 0.f;
  #pragma unroll
  for (int p = 0; p < 8; p++) s += po[((size_t)p*NQ + q)*CDIM + tid];

  if (tid < 64){
    int p = tid >> 3, h = tid & 7;
    float l = pl[((size_t)p*NQ + q)*NH + h];
    l += __shfl_xor(l, 8);
    l += __shfl_xor(l, 16);
    l += __shfl_xor(l, 32);
    if (p == 0) linv[h] = 1.0f / l;
  }
  __syncthreads();
  a_lds[tid] = s * linv[tid >> 5];
  __syncthreads();

  const float4* wrow = (const float4*)(Wo + (size_t)tid*CDIM);
  const float4* av = (const float4*)a_lds;
  float acc0 = bo[tid], acc1 = 0.f, acc2 = 0.f, acc3 = 0.f;
  #pragma unroll 4
  for (int c = 0; c < 64; c += 4){
    float4 w0 = wrow[c+0], a0 = av[c+0];
    float4 w1 = wrow[c+1], a1 = av[c+1];
    float4 w2 = wrow[c+2], a2 = av[c+2];
    float4 w3 = wrow[c+3], a3 = av[c+3];
    acc0 = fmaf(w0.x,a0.x,fmaf(w0.y,a0.y,fmaf(w0.z,a0.z,fmaf(w0.w,a0.w,acc0))));
    acc1 = fmaf(w1.x,a1.x,fmaf(w1.y,a1.y,fmaf(w1.z,a1.z,fmaf(w1.w,a1.w,acc1))));
    acc2 = fmaf(w2.x,a2.x,fmaf(w2.y,a2.y,fmaf(w2.z,a2.z,fmaf(w2.w,a2.w,acc2))));
    acc3 = fmaf(w3.x,a3.x,fmaf(w3.y,a3.y,fmaf(w3.z,a3.z,fmaf(w3.w,a3.w,acc3))));
  }
  dout[(size_t)q*CDIM + tid] = acc0 + acc1 + acc2 + acc3;
}

extern "C" void kernel_launch(void* const* d_in, const int* in_sizes, int n_in,
                              void* d_out, int out_size, void* d_ws, size_t ws_size,
                              hipStream_t stream)
{
  const float* rq  = (const float*)d_in[0];
  const float* qp  = (const float*)d_in[1];
  const float* rp  = (const float*)d_in[2];
  const float* rs  = (const float*)d_in[3];
  const float* spe = (const float*)d_in[4];
  const float* Wq  = (const float*)d_in[5];
  const float* bq  = (const float*)d_in[6];
  const float* Wk  = (const float*)d_in[7];
  const float* bk  = (const float*)d_in[8];
  const float* Wv  = (const float*)d_in[9];
  const float* bv  = (const float*)d_in[10];
  const float* Wo  = (const float*)d_in[11];
  const float* bo  = (const float*)d_in[12];
  const float* W1  = (const float*)d_in[13];
  const float* b1  = (const float*)d_in[14];
  const float* W2  = (const float*)d_in[15];
  char* ws = (char*)d_ws;
  float* dout = (float*)d_out;

  proj_kernel<<<912, 256, 0, stream>>>(rq, qp, rs, spe, Wq, bq, Wk, bk,
      Wv, bv, rp, W1, b1, W2, ws);
  fused_kernel<<<2400, 256, 0, stream>>>((const short*)(ws + A16_OFF),
      (const short*)(ws + NX_OFF), (const short*)(ws + NY_OFF),
      (const short*)(ws + W2_OFF), (const short*)(ws + QB_OFF),
      (const short*)(ws + KB_OFF), (const short*)(ws + VT_OFF),
      (float*)(ws + PO_OFF), (float*)(ws + PL_OFF));
  outproj_kernel<<<300, 256, 0, stream>>>((const float*)(ws + PO_OFF),
      (const float*)(ws + PL_OFF), Wo, bo, dout);
}

// Round 9
// 144.552 us; speedup vs baseline: 4.0352x; 1.1014x over previous
//
#include <hip/hip_runtime.h>
#include <hip/hip_fp16.h>
#include <stdint.h>

#define NQ   300
#define CDIM 256
#define NH   8
#define HD   32
#define HWK  1024
#define HIDD 512

typedef __attribute__((ext_vector_type(8))) _Float16 f16x8;
typedef __attribute__((ext_vector_type(2))) _Float16 h2v;
typedef __attribute__((ext_vector_type(4))) float f32x4;

// ---- ws byte offsets ----
#define QB_OFF   0          // 300*256 f16 [q][c], scale folded
#define KB_OFF   153600     // 8*1024*32 f16 [h][k][d]
#define VT_OFF   677888     // [256 ch][1024 k] f16
#define A16_OFF  3736576    // [300][512] f16 a(q,f)
#define NX_OFF   4043776    // [512] f16 -wx
#define NY_OFF   4044800    // [512] f16 -wy
#define W2_OFF   4045824    // [8][512] f16 W2
#define PO_OFF   4200448    // [16 kr][300 q][256 c] f32 partial O (4.9MB)
#define PL_OFF   9120000    // [16 kr][300 q][8 h] f32 partial exp-sums

__device__ __forceinline__ short f16b(float x){
  _Float16 h = (_Float16)x;
  return __builtin_bit_cast(short, h);
}

__device__ __forceinline__ uint32_t pk_f16(float a, float b){
  auto r = __builtin_amdgcn_cvt_pkrtz(a, b);
  return __builtin_bit_cast(uint32_t, r);
}

// ---------------- projection GEMMs + fused prep blocks (round-2 verified) ----------------
__global__ __launch_bounds__(256) void proj_kernel(
    const float* __restrict__ rq, const float* __restrict__ qp,
    const float* __restrict__ rs, const float* __restrict__ spe,
    const float* __restrict__ Wq, const float* __restrict__ bq,
    const float* __restrict__ Wk, const float* __restrict__ bk,
    const float* __restrict__ Wv, const float* __restrict__ bv,
    const float* __restrict__ refp, const float* __restrict__ W1,
    const float* __restrict__ b1, const float* __restrict__ W2,
    char* __restrict__ ws)
{
  int bxid = blockIdx.x;
  __shared__ __align__(16) float At[32][20];
  __shared__ float Wl[32][129];

  if (bxid >= 294){
    // ---- prep path ----
    int idx = (bxid - 294) * 256 + threadIdx.x;
    short* a16  = (short*)(ws + A16_OFF);
    short* nx16 = (short*)(ws + NX_OFF);
    short* ny16 = (short*)(ws + NY_OFF);
    short* w216 = (short*)(ws + W2_OFF);
    if (idx < NQ*HIDD){
      int q = idx >> 9, f = idx & 511;
      float2 w = ((const float2*)W1)[f];
      float a = fmaf(w.x, refp[2*q], fmaf(w.y, refp[2*q+1], b1[f]));
      a16[idx] = f16b(a);
    } else {
      int j = idx - NQ*HIDD;
      if (j < HIDD){
        float2 w = ((const float2*)W1)[j];
        nx16[j] = f16b(-w.x);
        ny16[j] = f16b(-w.y);
      } else if (j < HIDD + NH*HIDD){
        int e = j - HIDD;
        w216[e] = f16b(W2[e]);
      }
    }
    return;
  }

  int tile = bxid >> 1, half = bxid & 1;
  const float *in1, *in2, *W, *bias;
  int r0, M, mode;
  if (tile < 19){
    in1 = rq; in2 = qp; W = Wq; bias = bq; r0 = tile*16; M = NQ; mode = 0;
  } else if (tile < 83){
    in1 = rs; in2 = spe; W = Wk; bias = bk; r0 = (tile-19)*16; M = HWK; mode = 1;
  } else {
    in1 = rs; in2 = spe; W = Wv; bias = bv; r0 = (tile-83)*16; M = HWK; mode = 2;
  }
  int tid = threadIdx.x;
  int n_loc = tid & 127;
  int rg = tid >> 7;
  int n = half*128 + n_loc;
  float acc[8];
  float bv_ = bias[n];
  #pragma unroll
  for (int i=0;i<8;i++) acc[i] = bv_;

  for (int c0 = 0; c0 < CDIM; c0 += 32){
    __syncthreads();
    for (int e = tid; e < 512; e += 256){
      int r = e >> 5, c = e & 31;
      int gr = r0 + r; if (gr >= M) gr = M - 1;
      At[c][r] = in1[gr*CDIM + c0 + c] + in2[gr*CDIM + c0 + c];
    }
    for (int e = tid; e < 4096; e += 256){
      int c = e & 31, nn = e >> 5;
      Wl[c][nn] = W[(half*128 + nn)*CDIM + c0 + c];
    }
    __syncthreads();
    #pragma unroll
    for (int c = 0; c < 32; c++){
      float w = Wl[c][n_loc];
      const float4* ap = (const float4*)&At[c][rg*8];
      float4 a0 = ap[0], a1 = ap[1];
      acc[0] = fmaf(a0.x, w, acc[0]);
      acc[1] = fmaf(a0.y, w, acc[1]);
      acc[2] = fmaf(a0.z, w, acc[2]);
      acc[3] = fmaf(a0.w, w, acc[3]);
      acc[4] = fmaf(a1.x, w, acc[4]);
      acc[5] = fmaf(a1.y, w, acc[5]);
      acc[6] = fmaf(a1.z, w, acc[6]);
      acc[7] = fmaf(a1.w, w, acc[7]);
    }
  }

  if (mode == 0){
    short* qb = (short*)(ws + QB_OFF);
    const float s = 0.17677669529663687f;  // 1/sqrt(32)
    #pragma unroll
    for (int i=0;i<8;i++){
      int gr = r0 + rg*8 + i;
      if (gr < M) qb[gr*CDIM + n] = f16b(acc[i]*s);
    }
  } else if (mode == 1){
    short* kb = (short*)(ws + KB_OFF);
    int h = n >> 5, d = n & 31;
    #pragma unroll
    for (int i=0;i<8;i++){
      int gr = r0 + rg*8 + i;
      if (gr < M) kb[((size_t)h*HWK + gr)*HD + d] = f16b(acc[i]);
    }
  } else {
    short* vt = (short*)(ws + VT_OFF);
    uint32_t p[4];
    #pragma unroll
    for (int i=0;i<4;i++) p[i] = pk_f16(acc[2*i], acc[2*i+1]);
    *(uint4*)(vt + n*HWK + r0 + rg*8) = make_uint4(p[0], p[1], p[2], p[3]);
  }
}

// ---------------- fused: 2 queries/block, 16 kr slabs of 64 keys -> grid 2400 ----------------
// qpair = bid>>4 (q0 = 2*qpair), kr = bid&15. 4 waves: wave w owns kyrow
// r = w&1 (global kyrow kr*2+r) and kx-half th = w>>1 (kx th*16 + n).
// Work-preserving split of the round-2 unit: per-block work halves, blocks double.
__global__ __launch_bounds__(256, 6) void fused_kernel(
    const short* __restrict__ a16, const short* __restrict__ nx16,
    const short* __restrict__ ny16, const short* __restrict__ w216,
    const short* __restrict__ qb, const short* __restrict__ kb,
    const short* __restrict__ vt, float* __restrict__ po,
    float* __restrict__ pl)
{
  int bid = blockIdx.x;
  int q0 = (bid >> 4) * 2, kr = bid & 15;
  int tid = threadIdx.x, wave = tid >> 6, lane = tid & 63;
  int n = lane & 15, qd = lane >> 4;
  int r = wave & 1, th = wave >> 1;

  __shared__ __align__(16) _Float16 nwx[HIDD];        // 1KB
  __shared__ __align__(16) _Float16 c1s[2][2][HIDD];  // [qq][row][f], 4KB
  __shared__ __align__(16) _Float16 w2l[NH][520];     // 8.3KB
  __shared__ __align__(16) _Float16 pb[2][NH][72];    // [qq][h][64 keys + pad], 2.3KB
  __shared__ __align__(16) float part[2][4][NH][16];  // [qq][wave][h][n], 4KB
  __shared__ float lsum[4][16];

  // ---- staging from f16 tables ----
  {
    int f0 = tid * 2;
    h2v ny2 = *(const h2v*)(ny16 + f0);
    h2v nx2 = *(const h2v*)(nx16 + f0);
    *(h2v*)&nwx[f0] = nx2;
    #pragma unroll
    for (int qq = 0; qq < 2; qq++){
      h2v a2 = *(const h2v*)(a16 + (q0+qq)*HIDD + f0);
      #pragma unroll
      for (int rr = 0; rr < 2; rr++){
        _Float16 kyh = (_Float16)(((float)(kr*2 + rr) + 0.5f) * (1.0f/32.0f));
        h2v ky2 = {kyh, kyh};
        *(h2v*)&c1s[qq][rr][f0] = ny2 * ky2 + a2;    // v_pk_fma_f16
      }
    }
  }
  for (int e = tid; e < 512; e += 256){
    int rw = e >> 6, c = e & 63;
    *(f16x8*)&w2l[rw][c*8] = *(const f16x8*)(w216 + rw*HIDD + c*8);
  }
  // masked q fragments: col n = query (n>>3), head (n&7)
  f16x8 qfrag = *(const f16x8*)(qb + (q0 + (n >> 3))*CDIM + (n & 7)*HD + qd*8);
  f16x8 qm[NH];
  #pragma unroll
  for (int h = 0; h < NH; h++){
    f16x8 z = {0,0,0,0,0,0,0,0};
    qm[h] = ((n & 7) == h) ? qfrag : z;
  }
  __syncthreads();

  const int kyrow = kr*2 + r;             // global ky row (0..31)
  const int k0 = kyrow*32 + th*16;        // wave's 16-key tile base

  // ---- phase 1: logits for both queries (one 16-key tile per wave) ----
  f32x4 acc1 = {0.f,0.f,0.f,0.f};
  #pragma unroll
  for (int h = 0; h < NH; h++){
    f16x8 af = *(const f16x8*)(kb + ((size_t)h*HWK + k0 + n)*HD + qd*8);
    acc1 = __builtin_amdgcn_mfma_f32_16x16x32_f16(af, qm[h], acc1, 0, 0, 0);
  }

  // ---- phase 2: 2 chains accb[qq] += relu(c1_qq - wx*kx) @ W2^T ----
  _Float16 kxh = (_Float16)(((float)(th*16 + n) + 0.5f) * (1.0f/32.0f));
  f16x8 kx8, z8;
  #pragma unroll
  for (int j = 0; j < 8; j++){ kx8[j] = kxh; z8[j] = (_Float16)0.f; }
  f32x4 accb[2];
  accb[0] = acc1; accb[1] = acc1;
  const _Float16* c1r0 = &c1s[0][r][0];
  const _Float16* c1r1 = &c1s[1][r][0];
  #pragma unroll 4
  for (int kc = 0; kc < 16; kc++){
    int ff = kc*32 + qd*8;
    f16x8 c10 = *(const f16x8*)(c1r0 + ff);
    f16x8 c11 = *(const f16x8*)(c1r1 + ff);
    f16x8 wxv = *(const f16x8*)(&nwx[ff]);
    f16x8 bfr = *(const f16x8*)(&w2l[n & 7][ff]);
    f16x8 e0 = __builtin_elementwise_max(wxv * kx8 + c10, z8);
    accb[0] = __builtin_amdgcn_mfma_f32_16x16x32_f16(e0, bfr, accb[0], 0, 0, 0);
    f16x8 e1 = __builtin_elementwise_max(wxv * kx8 + c11, z8);
    accb[1] = __builtin_amdgcn_mfma_f32_16x16x32_f16(e1, bfr, accb[1], 0, 0, 0);
  }

  // ---- phase 3: exp (no max-subtract), pb f16, l partials ----
  int qsel = n >> 3, hsel = n & 7;
  float lacc;
  {
    f32x4 a = qsel ? accb[1] : accb[0];
    float e0 = __expf(a[0]);
    float e1 = __expf(a[1]);
    float e2 = __expf(a[2]);
    float e3 = __expf(a[3]);
    uint2 p2;
    p2.x = pk_f16(e0, e1);
    p2.y = pk_f16(e2, e3);
    *(uint2*)&pb[qsel][hsel][r*32 + th*16 + qd*4] = p2;
    float s = e0 + e1 + e2 + e3;
    s += __shfl_xor(s, 16);
    s += __shfl_xor(s, 32);
    lacc = s;
  }
  if (lane < 16) lsum[wave][lane] = lacc;
  __syncthreads();   // pb is cross-wave in phase 4 (chunk spans both th halves)

  // ---- phase 4: PV — wave w: key chunk c = w&1 (32 keys), out-half oh = w>>1 ----
  {
    int c = wave & 1, oh = wave >> 1;
    #pragma unroll
    for (int h = 0; h < NH; h++){
      f16x8 pa = *(const f16x8*)&pb[n & 1][h][c*32 + qd*8];
      f16x8 v0 = *(const f16x8*)(vt + ((size_t)(h*HD + oh*16 + n))*HWK + kr*64 + c*32 + qd*8);
      f32x4 o0 = {0.f,0.f,0.f,0.f};
      o0 = __builtin_amdgcn_mfma_f32_16x16x32_f16(pa, v0, o0, 0, 0, 0);
      if (qd == 0){
        part[0][wave][h][n] = o0[0];   // D row 0 = q0
        part[1][wave][h][n] = o0[1];   // D row 1 = q1
      }
    }
  }
  __syncthreads();

  // ---- combine waves, write partials for both queries ----
  {
    int h = tid >> 5, d = tid & 31;
    int oh = d >> 4, dn = d & 15;
    #pragma unroll
    for (int qq = 0; qq < 2; qq++){
      float s = part[qq][oh*2 + 0][h][dn] + part[qq][oh*2 + 1][h][dn];
      po[((size_t)kr*NQ + q0 + qq)*CDIM + tid] = s;
    }
    if (tid < 16){
      float s = lsum[0][tid] + lsum[1][tid] + lsum[2][tid] + lsum[3][tid];
      pl[((size_t)kr*NQ + q0 + (tid >> 3))*NH + (tid & 7)] = s;
    }
  }
}

// ---------------- output projection: one block per query row, 16 partials ----------------
__global__ __launch_bounds__(256) void outproj_kernel(
    const float* __restrict__ po, const float* __restrict__ pl,
    const float* __restrict__ Wo, const float* __restrict__ bo,
    float* __restrict__ dout)
{
  int q = blockIdx.x;
  int tid = threadIdx.x;
  __shared__ __align__(16) float a_lds[CDIM];
  __shared__ float linv[NH];

  float s = 0.f;
  #pragma unroll
  for (int p = 0; p < 16; p++) s += po[((size_t)p*NQ + q)*CDIM + tid];

  if (tid < 64){
    int p = tid >> 3, h = tid & 7;
    float l = pl[((size_t)p*NQ + q)*NH + h]
            + pl[((size_t)(p+8)*NQ + q)*NH + h];
    l += __shfl_xor(l, 8);
    l += __shfl_xor(l, 16);
    l += __shfl_xor(l, 32);
    if (p == 0) linv[h] = 1.0f / l;
  }
  __syncthreads();
  a_lds[tid] = s * linv[tid >> 5];
  __syncthreads();

  const float4* wrow = (const float4*)(Wo + (size_t)tid*CDIM);
  const float4* av = (const float4*)a_lds;
  float acc0 = bo[tid], acc1 = 0.f, acc2 = 0.f, acc3 = 0.f;
  #pragma unroll 4
  for (int c = 0; c < 64; c += 4){
    float4 w0 = wrow[c+0], a0 = av[c+0];
    float4 w1 = wrow[c+1], a1 = av[c+1];
    float4 w2 = wrow[c+2], a2 = av[c+2];
    float4 w3 = wrow[c+3], a3 = av[c+3];
    acc0 = fmaf(w0.x,a0.x,fmaf(w0.y,a0.y,fmaf(w0.z,a0.z,fmaf(w0.w,a0.w,acc0))));
    acc1 = fmaf(w1.x,a1.x,fmaf(w1.y,a1.y,fmaf(w1.z,a1.z,fmaf(w1.w,a1.w,acc1))));
    acc2 = fmaf(w2.x,a2.x,fmaf(w2.y,a2.y,fmaf(w2.z,a2.z,fmaf(w2.w,a2.w,acc2))));
    acc3 = fmaf(w3.x,a3.x,fmaf(w3.y,a3.y,fmaf(w3.z,a3.z,fmaf(w3.w,a3.w,acc3))));
  }
  dout[(size_t)q*CDIM + tid] = acc0 + acc1 + acc2 + acc3;
}

extern "C" void kernel_launch(void* const* d_in, const int* in_sizes, int n_in,
                              void* d_out, int out_size, void* d_ws, size_t ws_size,
                              hipStream_t stream)
{
  const float* rq  = (const float*)d_in[0];
  const float* qp  = (const float*)d_in[1];
  const float* rp  = (const float*)d_in[2];
  const float* rs  = (const float*)d_in[3];
  const float* spe = (const float*)d_in[4];
  const float* Wq  = (const float*)d_in[5];
  const float* bq  = (const float*)d_in[6];
  const float* Wk  = (const float*)d_in[7];
  const float* bk  = (const float*)d_in[8];
  const float* Wv  = (const float*)d_in[9];
  const float* bv  = (const float*)d_in[10];
  const float* Wo  = (const float*)d_in[11];
  const float* bo  = (const float*)d_in[12];
  const float* W1  = (const float*)d_in[13];
  const float* b1  = (const float*)d_in[14];
  const float* W2  = (const float*)d_in[15];
  char* ws = (char*)d_ws;
  float* dout = (float*)d_out;

  proj_kernel<<<912, 256, 0, stream>>>(rq, qp, rs, spe, Wq, bq, Wk, bk,
      Wv, bv, rp, W1, b1, W2, ws);
  fused_kernel<<<2400, 256, 0, stream>>>((const short*)(ws + A16_OFF),
      (const short*)(ws + NX_OFF), (const short*)(ws + NY_OFF),
      (const short*)(ws + W2_OFF), (const short*)(ws + QB_OFF),
      (const short*)(ws + KB_OFF), (const short*)(ws + VT_OFF),
      (float*)(ws + PO_OFF), (float*)(ws + PL_OFF));
  outproj_kernel<<<300, 256, 0, stream>>>((const float*)(ws + PO_OFF),
      (const float*)(ws + PL_OFF), Wo, bo, dout);
}